// Round 11
// baseline (1328.881 us; speedup 1.0000x reference)
//
#include <hip/hip_runtime.h>
#include <hip/hip_bf16.h>

typedef __hip_bfloat16 bf16;
typedef __attribute__((ext_vector_type(8))) short bf16x8;
typedef __attribute__((ext_vector_type(4))) float f32x4;

#define NNODE 512   // B*N

__device__ __forceinline__ float b2f(bf16 v){ return __bfloat162float(v); }
__device__ __forceinline__ float siluf(float x){ return x / (1.f + __expf(-x)); }
__device__ __forceinline__ float tanhfast(float x){ return 1.f - 2.f/(__expf(2.f*x)+1.f); }
__device__ __forceinline__ float celu2(float x){ return x > 0.f ? x : 2.f*(__expf(0.5f*x)-1.f); }
__device__ __forceinline__ float bs2f(short v){ union{unsigned int i; float f;} t; t.i = ((unsigned int)(unsigned short)v) << 16; return t.f; }
__device__ __forceinline__ short f2bs(float x){ union{ bf16 b; short s; } u; u.b = __float2bfloat16(x); return u.s; }

// ---- dtype-polymorphic scalar load/store -------------------------------------------
template<typename T> __device__ __forceinline__ float ldv(const void* p, int i);
template<> __device__ __forceinline__ float ldv<float>(const void* p, int i){ return ((const float*)p)[i]; }
template<> __device__ __forceinline__ float ldv<bf16 >(const void* p, int i){ return b2f(((const bf16*)p)[i]); }

template<typename T> __device__ __forceinline__ void stv(void* p, int i, float v);
template<> __device__ __forceinline__ void stv<float>(void* p, int i, float v){ ((float*)p)[i] = v; }
template<> __device__ __forceinline__ void stv<bf16 >(void* p, int i, float v){ ((bf16*)p)[i] = __float2bfloat16(v); }

// load one element as bf16 bit-pattern (short)
template<typename T> __device__ __forceinline__ short ldbs(const void* p, int i);
template<> __device__ __forceinline__ short ldbs<bf16 >(const void* p, int i){ union{ bf16 b; short s; } u; u.b = ((const bf16*)p)[i]; return u.s; }
template<> __device__ __forceinline__ short ldbs<float>(const void* p, int i){ return f2bs(((const float*)p)[i]); }

struct Args {
    const void *h,*x,*v,*Win,*bin,*means,*betas,*Wo1,*bo1,*Wo2,*bo2,*Wsem,*bsem,*Wx,
               *Wp1,*bp1,*Wp2,*bp2,*Wn1,*bn1,*Wn2,*bn2,*Wv1,*bv1,*Wv2,*Wvm;
};

// ---- dtype detector: rbf_means[0] ~ 0.0067; read as bf16 low-half of an f32 it is huge
__global__ void k_detect(const void* means, int* flag){
    if (threadIdx.x == 0){
        float v = b2f(((const bf16*)means)[0]);
        flag[0] = (fabsf(v) > 1.0f || v != v) ? 1 : 0;   // 1 => inputs are float32
    }
}

// ---- fused SAKE layer: one block per (b,i) node; 256 threads (4 waves) -------------
// R10 base (best passing: 1124us) + __launch_bounds__(256,2): cap 256 total regs
// (VGPR+AGPR unified on gfx950; R10's 224 VGPR + 64 AGPR = 288 > 256 meant only
//  1 wave/SIMD resident -> OccupancyPercent 12%, pure latency-bound).
template<typename T, int WANT>
__global__ void __launch_bounds__(256, 2) k_sake(Args A, const int* __restrict__ flag,
                                                 void* __restrict__ out)
{
    if (flag[0] != WANT) return;

    int bi = blockIdx.x;
    int b = bi >> 8, i = bi & 255;
    int tid = threadIdx.x, w = tid >> 6, lane = tid & 63;

    __shared__ float s_hi[64];           // h_i                          256 B
    __shared__ float s_h[16][64];        // h_j tile per pass              4 KB
    __shared__ bf16  s_e[256][66];       // edge features (row padded)  33.8 KB
    __shared__ float s_att[256][4];      // logits -> softmax weights      4 KB
    __shared__ float s_x4[256][4];       // xhat[3], d                     4 KB
    __shared__ float s_rbfh[4][4][52];   //                              3.3 KB
    __shared__ float s_mid[4][4][64];    //                                4 KB
    __shared__ float s_sm[1024];         // softmax scratch                4 KB
    __shared__ float s_red[768];         // comb_sum result                3 KB
    __shared__ float s_he[256];          // h_e                            1 KB
    __shared__ float s_cn[256];          // comb_norm                      1 KB
    __shared__ float s_f1[64], s_f2[64], s_f3[64], s_f4[64];  //           1 KB

    s_red[tid] = 0.f; s_red[tid+256] = 0.f; s_red[tid+512] = 0.f;
    if (tid < 64) s_hi[tid] = ldv<T>(A.h, bi*64 + tid);
    __syncthreads();

    float xi0 = ldv<T>(A.x, bi*3+0), xi1 = ldv<T>(A.x, bi*3+1), xi2 = ldv<T>(A.x, bi*3+2);

    // per-lane i-side constants
    float bo1v  = ldv<T>(A.bo1, lane);
    float wlast = ldv<T>(A.Wo1, 178*64 + lane);
    float bo2v  = ldv<T>(A.bo2, lane);
    float u2v = 0.f;
    for (int f = 0; f < 64; ++f) u2v += s_hi[f] * ldv<T>(A.Wo1, (64+f)*64 + lane);
    float muv = 0.f, bev = 0.f, binv = 0.f, aiv = 0.f;
    if (lane < 50){
        muv = ldv<T>(A.means, lane); bev = ldv<T>(A.betas, lane); binv = ldv<T>(A.bin, lane);
        for (int f = 0; f < 64; ++f) aiv += s_hi[f] * ldv<T>(A.Win, (64+f)*50 + lane);
    }

    // ================= edge phase: 16 passes x (4 waves x 4 pairs) =================
    for (int pass = 0; pass < 16; ++pass){
        int j0g = pass*16;
        #pragma unroll
        for (int q = 0; q < 4; ++q){
            int idx = q*256 + tid;   // 0..1023
            s_h[idx>>6][idx&63] = ldv<T>(A.h, (b*256 + j0g)*64 + idx);
        }
        __syncthreads();

        int j0 = j0g + w*4;
        float dist[4];
        #pragma unroll
        for (int pp = 0; pp < 4; ++pp){
            int j = j0 + pp;
            float dx = ldv<T>(A.x,(b*256+j)*3+0) - xi0;
            float dy = ldv<T>(A.x,(b*256+j)*3+1) - xi1;
            float dz = ldv<T>(A.x,(b*256+j)*3+2) - xi2;
            float dd = sqrtf(dx*dx + dy*dy + dz*dz + 1e-5f);
            dist[pp] = dd;
            if (lane == 0){
                float inv = 1.f/(dd + 1e-5f);
                s_x4[j][0] = dx*inv; s_x4[j][1] = dy*inv; s_x4[j][2] = dz*inv; s_x4[j][3] = dd;
            }
        }
        if (lane < 50){
            #pragma unroll
            for (int pp = 0; pp < 4; ++pp){
                const float* hj = s_h[w*4+pp];
                float aj = 0.f;
                for (int f = 0; f < 64; ++f) aj += hj[f] * ldv<T>(A.Win, f*50 + lane);
                float h1 = aj + aiv + binv;
                float dd = dist[pp];
                float cut = (dd < 5.f) ? 0.5f*(__cosf(dd*0.6283185307f) + 1.f) : 0.f;
                float ex = __expf(-dd) - muv;
                s_rbfh[w][pp][lane] = cut * __expf(-bev*ex*ex) * h1;
            }
        }
        __syncthreads();

        // o1 = U1[j] (inline) + U2[i] + b_o1 + d*w_last + rbf*h1 part
        float acc[4];
        #pragma unroll
        for (int pp = 0; pp < 4; ++pp) acc[pp] = u2v + bo1v + dist[pp]*wlast;
        for (int f = 0; f < 64; ++f){
            float wv = ldv<T>(A.Wo1, f*64 + lane);
            #pragma unroll
            for (int pp = 0; pp < 4; ++pp) acc[pp] += s_h[w*4+pp][f] * wv;
        }
        for (int k = 0; k < 50; ++k){
            float wv = ldv<T>(A.Wo1, (128+k)*64 + lane);
            #pragma unroll
            for (int pp = 0; pp < 4; ++pp) acc[pp] += s_rbfh[w][pp][k] * wv;
        }
        #pragma unroll
        for (int pp = 0; pp < 4; ++pp) s_mid[w][pp][lane] = siluf(acc[pp]);
        __syncthreads();

        // o2
        float acc2[4] = {bo2v, bo2v, bo2v, bo2v};
        for (int k = 0; k < 64; ++k){
            float wv = ldv<T>(A.Wo2, k*64 + lane);
            #pragma unroll
            for (int pp = 0; pp < 4; ++pp) acc2[pp] += s_mid[w][pp][k] * wv;
        }
        #pragma unroll
        for (int pp = 0; pp < 4; ++pp) s_e[j0+pp][lane] = __float2bfloat16(acc2[pp]);
        __syncthreads();
    }

    // ================= semantic attention logits (thread = j) =================
    {
        int j = tid;
        float a0 = ldv<T>(A.bsem,0), a1 = ldv<T>(A.bsem,1), a2 = ldv<T>(A.bsem,2), a3 = ldv<T>(A.bsem,3);
        for (int f = 0; f < 64; ++f){
            float ev = b2f(s_e[j][f]);
            a0 += ev * ldv<T>(A.Wsem, f*4+0);
            a1 += ev * ldv<T>(A.Wsem, f*4+1);
            a2 += ev * ldv<T>(A.Wsem, f*4+2);
            a3 += ev * ldv<T>(A.Wsem, f*4+3);
        }
        a0 = celu2(a0); a1 = celu2(a1); a2 = celu2(a2); a3 = celu2(a3);
        if (j == i){ a0 -= 1e5f; a1 -= 1e5f; a2 -= 1e5f; a3 -= 1e5f; }
        s_att[j][0] = a0; s_att[j][1] = a1; s_att[j][2] = a2; s_att[j][3] = a3;
    }
    __syncthreads();

    // ================= softmax over j (4 heads) =================
    {
        float l0 = s_att[tid][0], l1 = s_att[tid][1], l2 = s_att[tid][2], l3 = s_att[tid][3];
        s_sm[tid*4+0]=l0; s_sm[tid*4+1]=l1; s_sm[tid*4+2]=l2; s_sm[tid*4+3]=l3;
        __syncthreads();
        for (int off = 128; off > 0; off >>= 1){
            if (tid < off){
                s_sm[tid*4+0] = fmaxf(s_sm[tid*4+0], s_sm[(tid+off)*4+0]);
                s_sm[tid*4+1] = fmaxf(s_sm[tid*4+1], s_sm[(tid+off)*4+1]);
                s_sm[tid*4+2] = fmaxf(s_sm[tid*4+2], s_sm[(tid+off)*4+2]);
                s_sm[tid*4+3] = fmaxf(s_sm[tid*4+3], s_sm[(tid+off)*4+3]);
            }
            __syncthreads();
        }
        float m0 = s_sm[0], m1 = s_sm[1], m2 = s_sm[2], m3 = s_sm[3];
        __syncthreads();
        float e0 = __expf(l0-m0), e1 = __expf(l1-m1), e2 = __expf(l2-m2), e3 = __expf(l3-m3);
        s_sm[tid*4+0]=e0; s_sm[tid*4+1]=e1; s_sm[tid*4+2]=e2; s_sm[tid*4+3]=e3;
        __syncthreads();
        for (int off = 128; off > 0; off >>= 1){
            if (tid < off){
                s_sm[tid*4+0] += s_sm[(tid+off)*4+0];
                s_sm[tid*4+1] += s_sm[(tid+off)*4+1];
                s_sm[tid*4+2] += s_sm[(tid+off)*4+2];
                s_sm[tid*4+3] += s_sm[(tid+off)*4+3];
            }
            __syncthreads();
        }
        s_att[tid][0] = e0 / s_sm[0];
        s_att[tid][1] = e1 / s_sm[1];
        s_att[tid][2] = e2 / s_sm[2];
        s_att[tid][3] = e3 / s_sm[3];
    }
    __syncthreads();

    // ================= h_e[c] = sum_j e[j][f]*att[j][h], c = 4f+h =================
    {
        int f_he = tid >> 2, h_he = tid & 3;
        float he_acc = 0.f;
        for (int j2 = 0; j2 < 256; ++j2)
            he_acc += b2f(s_e[j2][f_he]) * s_att[j2][h_he];
        s_he[tid] = he_acc;
    }

    // ================= x-mixing via MFMA: P = A @ Wx, A[j,4f+h]=e[j][f]*att[j][h] ====
    // wave w owns c-slice [w*64, w*64+64). 16x16x32 bf16 MFMA.
    {
        int lane15 = lane & 15, quad = lane >> 4;
        int n0w = w*64;
        const short* se_s = (const short*)s_e;   // s_e[j][f] -> se_s[j*66+f]
        float comb_acc[4][3];
        #pragma unroll
        for (int nf = 0; nf < 4; ++nf){ comb_acc[nf][0]=0.f; comb_acc[nf][1]=0.f; comb_acc[nf][2]=0.f; }

        for (int jt = 0; jt < 4; ++jt){
            int jbase = jt*64;
            f32x4 Cc[4][4];
            #pragma unroll
            for (int mf = 0; mf < 4; ++mf)
                #pragma unroll
                for (int nf = 0; nf < 4; ++nf)
                    Cc[mf][nf] = (f32x4){0.f, 0.f, 0.f, 0.f};

            // att rows for this lane's 4 m-fragments (independent of kk)
            float am[4][4];
            #pragma unroll
            for (int mf = 0; mf < 4; ++mf){
                int jr = jbase + mf*16 + lane15;
                am[mf][0] = s_att[jr][0]; am[mf][1] = s_att[jr][1];
                am[mf][2] = s_att[jr][2]; am[mf][3] = s_att[jr][3];
            }

            for (int kk = 0; kk < 8; ++kk){
                // B fragments from Wx (row-major [k][n]); k = kk*32 + quad*8 + t
                bf16x8 Bf[4];
                #pragma unroll
                for (int nf = 0; nf < 4; ++nf){
                    int n = n0w + nf*16 + lane15;
                    int kb = (kk*32 + quad*8)*256 + n;
                    bf16x8 bv;
                    #pragma unroll
                    for (int t = 0; t < 8; ++t) bv[t] = ldbs<T>(A.Wx, kb + t*256);
                    Bf[nf] = bv;
                }
                // A fragments built from s_e and att
                int f0 = kk*8 + quad*2;
                bf16x8 Af[4];
                #pragma unroll
                for (int mf = 0; mf < 4; ++mf){
                    int jr = jbase + mf*16 + lane15;
                    float e0 = bs2f(se_s[jr*66 + f0]);
                    float e1 = bs2f(se_s[jr*66 + f0 + 1]);
                    bf16x8 av;
                    av[0]=f2bs(e0*am[mf][0]); av[1]=f2bs(e0*am[mf][1]);
                    av[2]=f2bs(e0*am[mf][2]); av[3]=f2bs(e0*am[mf][3]);
                    av[4]=f2bs(e1*am[mf][0]); av[5]=f2bs(e1*am[mf][1]);
                    av[6]=f2bs(e1*am[mf][2]); av[7]=f2bs(e1*am[mf][3]);
                    Af[mf] = av;
                }
                #pragma unroll
                for (int mf = 0; mf < 4; ++mf)
                    #pragma unroll
                    for (int nf = 0; nf < 4; ++nf)
                        Cc[mf][nf] = __builtin_amdgcn_mfma_f32_16x16x32_bf16(Af[mf], Bf[nf], Cc[mf][nf], 0, 0, 0);
            }

            // epilogue: tanh + weighted xhat accumulation
            #pragma unroll
            for (int mf = 0; mf < 4; ++mf){
                #pragma unroll
                for (int r = 0; r < 4; ++r){
                    int j = jbase + mf*16 + quad*4 + r;
                    float x0 = s_x4[j][0], x1 = s_x4[j][1], x2 = s_x4[j][2];
                    #pragma unroll
                    for (int nf = 0; nf < 4; ++nf){
                        float cf = tanhfast(Cc[mf][nf][r]);
                        comb_acc[nf][0] += cf*x0;
                        comb_acc[nf][1] += cf*x1;
                        comb_acc[nf][2] += cf*x2;
                    }
                }
            }
        }

        // reduce over quads (j-coverage) and store: each wave owns 64 c's
        #pragma unroll
        for (int nf = 0; nf < 4; ++nf){
            #pragma unroll
            for (int d = 0; d < 3; ++d){
                float vsum = comb_acc[nf][d];
                vsum += __shfl_xor(vsum, 16);
                vsum += __shfl_xor(vsum, 32);
                if (quad == 0) s_red[(n0w + nf*16 + lane15)*3 + d] = vsum;
            }
        }
    }
    __syncthreads();

    // ================= final per-node MLPs =================
    const float sc = 1.f/256.f;
    {
        float cb0 = s_red[tid*3+0]*sc, cb1 = s_red[tid*3+1]*sc, cb2 = s_red[tid*3+2]*sc;
        s_cn[tid] = cb0*cb0 + cb1*cb1 + cb2*cb2;
    }
    __syncthreads();

    if (tid < 64){
        int f = tid;
        float acc = ldv<T>(A.bp1, f);
        for (int c = 0; c < 256; ++c) acc += s_cn[c] * ldv<T>(A.Wp1, c*64 + f);
        s_f1[f] = siluf(acc);
    }
    __syncthreads();
    if (tid < 64){
        int f = tid;
        float acc = ldv<T>(A.bp2, f);
        for (int k = 0; k < 64; ++k) acc += s_f1[k] * ldv<T>(A.Wp2, k*64 + f);
        s_f2[f] = siluf(acc);
    }
    __syncthreads();
    if (tid < 64){
        int f = tid;
        float acc = ldv<T>(A.bn1, f);
        for (int r = 0; r < 64; ++r)  acc += s_hi[r] * ldv<T>(A.Wn1, r*64 + f);
        for (int r = 0; r < 256; ++r) acc += s_he[r] * ldv<T>(A.Wn1, (64+r)*64 + f);
        for (int r = 0; r < 64; ++r)  acc += s_f2[r] * ldv<T>(A.Wn1, (320+r)*64 + f);
        s_f3[f] = siluf(acc);
    }
    __syncthreads();
    if (tid < 64){
        int f = tid;
        float acc = ldv<T>(A.bn2, f);
        for (int k = 0; k < 64; ++k) acc += s_f3[k] * ldv<T>(A.Wn2, k*64 + f);
        float hn = s_hi[f] + siluf(acc);
        stv<T>(out, bi*64 + f, hn);
        s_f4[f] = hn;
    }
    __syncthreads();
    if (tid < 64){
        int f = tid;
        float acc = ldv<T>(A.bv1, f);
        for (int k = 0; k < 64; ++k) acc += s_f4[k] * ldv<T>(A.Wv1, k*64 + f);
        float term = siluf(acc) * ldv<T>(A.Wv2, f);
        #pragma unroll
        for (int off = 32; off > 0; off >>= 1) term += __shfl_down(term, off);
        float vscale = 2.f / (1.f + __expf(-__shfl(term, 0)));

        float dv0 = 0.f, dv1 = 0.f, dv2 = 0.f;
        #pragma unroll
        for (int q = 0; q < 4; ++q){
            int c = q*64 + f;
            float wv = ldv<T>(A.Wvm, c);
            dv0 += s_red[c*3+0]*sc*wv;
            dv1 += s_red[c*3+1]*sc*wv;
            dv2 += s_red[c*3+2]*sc*wv;
        }
        #pragma unroll
        for (int off = 32; off > 0; off >>= 1){
            dv0 += __shfl_down(dv0, off);
            dv1 += __shfl_down(dv1, off);
            dv2 += __shfl_down(dv2, off);
        }
        dv0 = __shfl(dv0, 0); dv1 = __shfl(dv1, 0); dv2 = __shfl(dv2, 0);
        if (f < 3){
            float dvl = (f == 0) ? dv0 : (f == 1 ? dv1 : dv2);
            float vn = dvl + vscale * ldv<T>(A.v, bi*3 + f);
            float xn = ldv<T>(A.x, bi*3 + f) + vn;
            stv<T>(out, 32768 + bi*3 + f, xn);  // x_new
            stv<T>(out, 34304 + bi*3 + f, vn);  // v_new
        }
    }
}

extern "C" void kernel_launch(void* const* d_in, const int* in_sizes, int n_in,
                              void* d_out, int out_size, void* d_ws, size_t ws_size,
                              hipStream_t stream)
{
    Args A;
    A.h     = d_in[0];  A.x     = d_in[1];  A.v     = d_in[2];
    A.Win   = d_in[3];  A.bin   = d_in[4];  A.means = d_in[5];  A.betas = d_in[6];
    A.Wo1   = d_in[7];  A.bo1   = d_in[8];  A.Wo2   = d_in[9];  A.bo2   = d_in[10];
    A.Wsem  = d_in[11]; A.bsem  = d_in[12]; A.Wx    = d_in[13];
    A.Wp1   = d_in[14]; A.bp1   = d_in[15]; A.Wp2   = d_in[16]; A.bp2   = d_in[17];
    A.Wn1   = d_in[18]; A.bn1   = d_in[19]; A.Wn2   = d_in[20]; A.bn2   = d_in[21];
    A.Wv1   = d_in[22]; A.bv1   = d_in[23]; A.Wv2   = d_in[24]; A.Wvm   = d_in[25];

    int* flag = (int*)d_ws;
    k_detect<<<1, 64, 0, stream>>>(A.means, flag);
    k_sake<bf16,  0><<<NNODE, 256, 0, stream>>>(A, flag, d_out);
    k_sake<float, 1><<<NNODE, 256, 0, stream>>>(A, flag, d_out);
}

// Round 12
// 1127.013 us; speedup vs baseline: 1.1791x; 1.1791x over previous
//
#include <hip/hip_runtime.h>
#include <hip/hip_bf16.h>

typedef __hip_bfloat16 bf16;
typedef __attribute__((ext_vector_type(8))) short bf16x8;
typedef __attribute__((ext_vector_type(4))) float f32x4;

#define NNODE 512   // B*N

__device__ __forceinline__ float b2f(bf16 v){ return __bfloat162float(v); }
__device__ __forceinline__ float siluf(float x){ return x / (1.f + __expf(-x)); }
__device__ __forceinline__ float tanhfast(float x){ return 1.f - 2.f/(__expf(2.f*x)+1.f); }
__device__ __forceinline__ float celu2(float x){ return x > 0.f ? x : 2.f*(__expf(0.5f*x)-1.f); }
__device__ __forceinline__ float bs2f(short v){ union{unsigned int i; float f;} t; t.i = ((unsigned int)(unsigned short)v) << 16; return t.f; }
__device__ __forceinline__ short f2bs(float x){ union{ bf16 b; short s; } u; u.b = __float2bfloat16(x); return u.s; }

// ---- dtype-polymorphic scalar load/store -------------------------------------------
template<typename T> __device__ __forceinline__ float ldv(const void* p, int i);
template<> __device__ __forceinline__ float ldv<float>(const void* p, int i){ return ((const float*)p)[i]; }
template<> __device__ __forceinline__ float ldv<bf16 >(const void* p, int i){ return b2f(((const bf16*)p)[i]); }

template<typename T> __device__ __forceinline__ void stv(void* p, int i, float v);
template<> __device__ __forceinline__ void stv<float>(void* p, int i, float v){ ((float*)p)[i] = v; }
template<> __device__ __forceinline__ void stv<bf16 >(void* p, int i, float v){ ((bf16*)p)[i] = __float2bfloat16(v); }

// load one element as bf16 bit-pattern (short)
template<typename T> __device__ __forceinline__ short ldbs(const void* p, int i);
template<> __device__ __forceinline__ short ldbs<bf16 >(const void* p, int i){ union{ bf16 b; short s; } u; u.b = ((const bf16*)p)[i]; return u.s; }
template<> __device__ __forceinline__ short ldbs<float>(const void* p, int i){ return f2bs(((const float*)p)[i]); }

struct Args {
    const void *h,*x,*v,*Win,*bin,*means,*betas,*Wo1,*bo1,*Wo2,*bo2,*Wsem,*bsem,*Wx,
               *Wp1,*bp1,*Wp2,*bp2,*Wn1,*bn1,*Wn2,*bn2,*Wv1,*bv1,*Wv2,*Wvm;
};

// ---- dtype detector: rbf_means[0] ~ 0.0067; read as bf16 low-half of an f32 it is huge
__global__ void k_detect(const void* means, int* flag){
    if (threadIdx.x == 0){
        float v = b2f(((const bf16*)means)[0]);
        flag[0] = (fabsf(v) > 1.0f || v != v) ? 1 : 0;   // 1 => inputs are float32
    }
}

// ---- fused SAKE layer: one block per (b,i) node; 256 threads (4 waves) -------------
// R10 base (1124us) with mixing accumulator halved: Cc[4][4] (64 AGPR) -> two
// sequential 32-column halves with Cc[4][2] (32 AGPR). Unified-file total goes
// 224+64=288 (1 wave/SIMD) -> 224+32=256 (2 waves/SIMD) with NO launch-bounds cap
// (R7/R9/R11 proved forced VGPR caps of 64/128 just spill 1.3-1.8 GB/dispatch).
template<typename T, int WANT>
__global__ void __launch_bounds__(256) k_sake(Args A, const int* __restrict__ flag,
                                              void* __restrict__ out)
{
    if (flag[0] != WANT) return;

    int bi = blockIdx.x;
    int b = bi >> 8, i = bi & 255;
    int tid = threadIdx.x, w = tid >> 6, lane = tid & 63;

    __shared__ float s_hi[64];           // h_i                          256 B
    __shared__ float s_h[16][64];        // h_j tile per pass              4 KB
    __shared__ bf16  s_e[256][66];       // edge features (row padded)  33.8 KB
    __shared__ float s_att[256][4];      // logits -> softmax weights      4 KB
    __shared__ float s_x4[256][4];       // xhat[3], d                     4 KB
    __shared__ float s_rbfh[4][4][52];   //                              3.3 KB
    __shared__ float s_mid[4][4][64];    //                                4 KB
    __shared__ float s_sm[1024];         // softmax scratch                4 KB
    __shared__ float s_red[768];         // comb_sum result                3 KB
    __shared__ float s_he[256];          // h_e                            1 KB
    __shared__ float s_cn[256];          // comb_norm                      1 KB
    __shared__ float s_f1[64], s_f2[64], s_f3[64], s_f4[64];  //           1 KB

    s_red[tid] = 0.f; s_red[tid+256] = 0.f; s_red[tid+512] = 0.f;
    if (tid < 64) s_hi[tid] = ldv<T>(A.h, bi*64 + tid);
    __syncthreads();

    float xi0 = ldv<T>(A.x, bi*3+0), xi1 = ldv<T>(A.x, bi*3+1), xi2 = ldv<T>(A.x, bi*3+2);

    // per-lane i-side constants
    float bo1v  = ldv<T>(A.bo1, lane);
    float wlast = ldv<T>(A.Wo1, 178*64 + lane);
    float bo2v  = ldv<T>(A.bo2, lane);
    float u2v = 0.f;
    for (int f = 0; f < 64; ++f) u2v += s_hi[f] * ldv<T>(A.Wo1, (64+f)*64 + lane);
    float muv = 0.f, bev = 0.f, binv = 0.f, aiv = 0.f;
    if (lane < 50){
        muv = ldv<T>(A.means, lane); bev = ldv<T>(A.betas, lane); binv = ldv<T>(A.bin, lane);
        for (int f = 0; f < 64; ++f) aiv += s_hi[f] * ldv<T>(A.Win, (64+f)*50 + lane);
    }

    // ================= edge phase: 16 passes x (4 waves x 4 pairs) =================
    for (int pass = 0; pass < 16; ++pass){
        int j0g = pass*16;
        #pragma unroll
        for (int q = 0; q < 4; ++q){
            int idx = q*256 + tid;   // 0..1023
            s_h[idx>>6][idx&63] = ldv<T>(A.h, (b*256 + j0g)*64 + idx);
        }
        __syncthreads();

        int j0 = j0g + w*4;
        float dist[4];
        #pragma unroll
        for (int pp = 0; pp < 4; ++pp){
            int j = j0 + pp;
            float dx = ldv<T>(A.x,(b*256+j)*3+0) - xi0;
            float dy = ldv<T>(A.x,(b*256+j)*3+1) - xi1;
            float dz = ldv<T>(A.x,(b*256+j)*3+2) - xi2;
            float dd = sqrtf(dx*dx + dy*dy + dz*dz + 1e-5f);
            dist[pp] = dd;
            if (lane == 0){
                float inv = 1.f/(dd + 1e-5f);
                s_x4[j][0] = dx*inv; s_x4[j][1] = dy*inv; s_x4[j][2] = dz*inv; s_x4[j][3] = dd;
            }
        }
        if (lane < 50){
            #pragma unroll
            for (int pp = 0; pp < 4; ++pp){
                const float* hj = s_h[w*4+pp];
                float aj = 0.f;
                for (int f = 0; f < 64; ++f) aj += hj[f] * ldv<T>(A.Win, f*50 + lane);
                float h1 = aj + aiv + binv;
                float dd = dist[pp];
                float cut = (dd < 5.f) ? 0.5f*(__cosf(dd*0.6283185307f) + 1.f) : 0.f;
                float ex = __expf(-dd) - muv;
                s_rbfh[w][pp][lane] = cut * __expf(-bev*ex*ex) * h1;
            }
        }
        __syncthreads();

        // o1 = U1[j] (inline) + U2[i] + b_o1 + d*w_last + rbf*h1 part
        float acc[4];
        #pragma unroll
        for (int pp = 0; pp < 4; ++pp) acc[pp] = u2v + bo1v + dist[pp]*wlast;
        for (int f = 0; f < 64; ++f){
            float wv = ldv<T>(A.Wo1, f*64 + lane);
            #pragma unroll
            for (int pp = 0; pp < 4; ++pp) acc[pp] += s_h[w*4+pp][f] * wv;
        }
        for (int k = 0; k < 50; ++k){
            float wv = ldv<T>(A.Wo1, (128+k)*64 + lane);
            #pragma unroll
            for (int pp = 0; pp < 4; ++pp) acc[pp] += s_rbfh[w][pp][k] * wv;
        }
        #pragma unroll
        for (int pp = 0; pp < 4; ++pp) s_mid[w][pp][lane] = siluf(acc[pp]);
        __syncthreads();

        // o2
        float acc2[4] = {bo2v, bo2v, bo2v, bo2v};
        for (int k = 0; k < 64; ++k){
            float wv = ldv<T>(A.Wo2, k*64 + lane);
            #pragma unroll
            for (int pp = 0; pp < 4; ++pp) acc2[pp] += s_mid[w][pp][k] * wv;
        }
        #pragma unroll
        for (int pp = 0; pp < 4; ++pp) s_e[j0+pp][lane] = __float2bfloat16(acc2[pp]);
        __syncthreads();
    }

    // ================= semantic attention logits (thread = j) =================
    {
        int j = tid;
        float a0 = ldv<T>(A.bsem,0), a1 = ldv<T>(A.bsem,1), a2 = ldv<T>(A.bsem,2), a3 = ldv<T>(A.bsem,3);
        for (int f = 0; f < 64; ++f){
            float ev = b2f(s_e[j][f]);
            a0 += ev * ldv<T>(A.Wsem, f*4+0);
            a1 += ev * ldv<T>(A.Wsem, f*4+1);
            a2 += ev * ldv<T>(A.Wsem, f*4+2);
            a3 += ev * ldv<T>(A.Wsem, f*4+3);
        }
        a0 = celu2(a0); a1 = celu2(a1); a2 = celu2(a2); a3 = celu2(a3);
        if (j == i){ a0 -= 1e5f; a1 -= 1e5f; a2 -= 1e5f; a3 -= 1e5f; }
        s_att[j][0] = a0; s_att[j][1] = a1; s_att[j][2] = a2; s_att[j][3] = a3;
    }
    __syncthreads();

    // ================= softmax over j (4 heads) =================
    {
        float l0 = s_att[tid][0], l1 = s_att[tid][1], l2 = s_att[tid][2], l3 = s_att[tid][3];
        s_sm[tid*4+0]=l0; s_sm[tid*4+1]=l1; s_sm[tid*4+2]=l2; s_sm[tid*4+3]=l3;
        __syncthreads();
        for (int off = 128; off > 0; off >>= 1){
            if (tid < off){
                s_sm[tid*4+0] = fmaxf(s_sm[tid*4+0], s_sm[(tid+off)*4+0]);
                s_sm[tid*4+1] = fmaxf(s_sm[tid*4+1], s_sm[(tid+off)*4+1]);
                s_sm[tid*4+2] = fmaxf(s_sm[tid*4+2], s_sm[(tid+off)*4+2]);
                s_sm[tid*4+3] = fmaxf(s_sm[tid*4+3], s_sm[(tid+off)*4+3]);
            }
            __syncthreads();
        }
        float m0 = s_sm[0], m1 = s_sm[1], m2 = s_sm[2], m3 = s_sm[3];
        __syncthreads();
        float e0 = __expf(l0-m0), e1 = __expf(l1-m1), e2 = __expf(l2-m2), e3 = __expf(l3-m3);
        s_sm[tid*4+0]=e0; s_sm[tid*4+1]=e1; s_sm[tid*4+2]=e2; s_sm[tid*4+3]=e3;
        __syncthreads();
        for (int off = 128; off > 0; off >>= 1){
            if (tid < off){
                s_sm[tid*4+0] += s_sm[(tid+off)*4+0];
                s_sm[tid*4+1] += s_sm[(tid+off)*4+1];
                s_sm[tid*4+2] += s_sm[(tid+off)*4+2];
                s_sm[tid*4+3] += s_sm[(tid+off)*4+3];
            }
            __syncthreads();
        }
        s_att[tid][0] = e0 / s_sm[0];
        s_att[tid][1] = e1 / s_sm[1];
        s_att[tid][2] = e2 / s_sm[2];
        s_att[tid][3] = e3 / s_sm[3];
    }
    __syncthreads();

    // ================= h_e[c] = sum_j e[j][f]*att[j][h], c = 4f+h =================
    {
        int f_he = tid >> 2, h_he = tid & 3;
        float he_acc = 0.f;
        for (int j2 = 0; j2 < 256; ++j2)
            he_acc += b2f(s_e[j2][f_he]) * s_att[j2][h_he];
        s_he[tid] = he_acc;
    }

    // ================= x-mixing via MFMA: P = A @ Wx, A[j,4f+h]=e[j][f]*att[j][h] ====
    // wave w owns c-slice [w*64, w*64+64), processed as TWO sequential 32-column
    // halves (Cc[4][2] = 32 AGPR instead of Cc[4][4] = 64) to fit 2 waves/SIMD.
    {
        int lane15 = lane & 15, quad = lane >> 4;
        const short* se_s = (const short*)s_e;   // s_e[j][f] -> se_s[j*66+f]

        for (int chalf = 0; chalf < 2; ++chalf){
            int n0 = w*64 + chalf*32;
            float comb_acc[2][3];
            #pragma unroll
            for (int nf = 0; nf < 2; ++nf){ comb_acc[nf][0]=0.f; comb_acc[nf][1]=0.f; comb_acc[nf][2]=0.f; }

            for (int jt = 0; jt < 4; ++jt){
                int jbase = jt*64;
                f32x4 Cc[4][2];
                #pragma unroll
                for (int mf = 0; mf < 4; ++mf)
                    #pragma unroll
                    for (int nf = 0; nf < 2; ++nf)
                        Cc[mf][nf] = (f32x4){0.f, 0.f, 0.f, 0.f};

                // att rows for this lane's 4 m-fragments (independent of kk)
                float am[4][4];
                #pragma unroll
                for (int mf = 0; mf < 4; ++mf){
                    int jr = jbase + mf*16 + lane15;
                    am[mf][0] = s_att[jr][0]; am[mf][1] = s_att[jr][1];
                    am[mf][2] = s_att[jr][2]; am[mf][3] = s_att[jr][3];
                }

                for (int kk = 0; kk < 8; ++kk){
                    // B fragments from Wx (row-major [k][n]); k = kk*32 + quad*8 + t
                    bf16x8 Bf[2];
                    #pragma unroll
                    for (int nf = 0; nf < 2; ++nf){
                        int n = n0 + nf*16 + lane15;
                        int kb = (kk*32 + quad*8)*256 + n;
                        bf16x8 bv;
                        #pragma unroll
                        for (int t = 0; t < 8; ++t) bv[t] = ldbs<T>(A.Wx, kb + t*256);
                        Bf[nf] = bv;
                    }
                    // A fragments built from s_e and att
                    int f0 = kk*8 + quad*2;
                    bf16x8 Af[4];
                    #pragma unroll
                    for (int mf = 0; mf < 4; ++mf){
                        int jr = jbase + mf*16 + lane15;
                        float e0 = bs2f(se_s[jr*66 + f0]);
                        float e1 = bs2f(se_s[jr*66 + f0 + 1]);
                        bf16x8 av;
                        av[0]=f2bs(e0*am[mf][0]); av[1]=f2bs(e0*am[mf][1]);
                        av[2]=f2bs(e0*am[mf][2]); av[3]=f2bs(e0*am[mf][3]);
                        av[4]=f2bs(e1*am[mf][0]); av[5]=f2bs(e1*am[mf][1]);
                        av[6]=f2bs(e1*am[mf][2]); av[7]=f2bs(e1*am[mf][3]);
                        Af[mf] = av;
                    }
                    #pragma unroll
                    for (int mf = 0; mf < 4; ++mf)
                        #pragma unroll
                        for (int nf = 0; nf < 2; ++nf)
                            Cc[mf][nf] = __builtin_amdgcn_mfma_f32_16x16x32_bf16(Af[mf], Bf[nf], Cc[mf][nf], 0, 0, 0);
                }

                // epilogue: tanh + weighted xhat accumulation
                #pragma unroll
                for (int mf = 0; mf < 4; ++mf){
                    #pragma unroll
                    for (int r = 0; r < 4; ++r){
                        int j = jbase + mf*16 + quad*4 + r;
                        float x0 = s_x4[j][0], x1 = s_x4[j][1], x2 = s_x4[j][2];
                        #pragma unroll
                        for (int nf = 0; nf < 2; ++nf){
                            float cf = tanhfast(Cc[mf][nf][r]);
                            comb_acc[nf][0] += cf*x0;
                            comb_acc[nf][1] += cf*x1;
                            comb_acc[nf][2] += cf*x2;
                        }
                    }
                }
            }

            // reduce over quads (j-coverage) and store this half's 32 c's
            #pragma unroll
            for (int nf = 0; nf < 2; ++nf){
                #pragma unroll
                for (int d = 0; d < 3; ++d){
                    float vsum = comb_acc[nf][d];
                    vsum += __shfl_xor(vsum, 16);
                    vsum += __shfl_xor(vsum, 32);
                    if (quad == 0) s_red[(n0 + nf*16 + lane15)*3 + d] = vsum;
                }
            }
        }
    }
    __syncthreads();

    // ================= final per-node MLPs =================
    const float sc = 1.f/256.f;
    {
        float cb0 = s_red[tid*3+0]*sc, cb1 = s_red[tid*3+1]*sc, cb2 = s_red[tid*3+2]*sc;
        s_cn[tid] = cb0*cb0 + cb1*cb1 + cb2*cb2;
    }
    __syncthreads();

    if (tid < 64){
        int f = tid;
        float acc = ldv<T>(A.bp1, f);
        for (int c = 0; c < 256; ++c) acc += s_cn[c] * ldv<T>(A.Wp1, c*64 + f);
        s_f1[f] = siluf(acc);
    }
    __syncthreads();
    if (tid < 64){
        int f = tid;
        float acc = ldv<T>(A.bp2, f);
        for (int k = 0; k < 64; ++k) acc += s_f1[k] * ldv<T>(A.Wp2, k*64 + f);
        s_f2[f] = siluf(acc);
    }
    __syncthreads();
    if (tid < 64){
        int f = tid;
        float acc = ldv<T>(A.bn1, f);
        for (int r = 0; r < 64; ++r)  acc += s_hi[r] * ldv<T>(A.Wn1, r*64 + f);
        for (int r = 0; r < 256; ++r) acc += s_he[r] * ldv<T>(A.Wn1, (64+r)*64 + f);
        for (int r = 0; r < 64; ++r)  acc += s_f2[r] * ldv<T>(A.Wn1, (320+r)*64 + f);
        s_f3[f] = siluf(acc);
    }
    __syncthreads();
    if (tid < 64){
        int f = tid;
        float acc = ldv<T>(A.bn2, f);
        for (int k = 0; k < 64; ++k) acc += s_f3[k] * ldv<T>(A.Wn2, k*64 + f);
        float hn = s_hi[f] + siluf(acc);
        stv<T>(out, bi*64 + f, hn);
        s_f4[f] = hn;
    }
    __syncthreads();
    if (tid < 64){
        int f = tid;
        float acc = ldv<T>(A.bv1, f);
        for (int k = 0; k < 64; ++k) acc += s_f4[k] * ldv<T>(A.Wv1, k*64 + f);
        float term = siluf(acc) * ldv<T>(A.Wv2, f);
        #pragma unroll
        for (int off = 32; off > 0; off >>= 1) term += __shfl_down(term, off);
        float vscale = 2.f / (1.f + __expf(-__shfl(term, 0)));

        float dv0 = 0.f, dv1 = 0.f, dv2 = 0.f;
        #pragma unroll
        for (int q = 0; q < 4; ++q){
            int c = q*64 + f;
            float wv = ldv<T>(A.Wvm, c);
            dv0 += s_red[c*3+0]*sc*wv;
            dv1 += s_red[c*3+1]*sc*wv;
            dv2 += s_red[c*3+2]*sc*wv;
        }
        #pragma unroll
        for (int off = 32; off > 0; off >>= 1){
            dv0 += __shfl_down(dv0, off);
            dv1 += __shfl_down(dv1, off);
            dv2 += __shfl_down(dv2, off);
        }
        dv0 = __shfl(dv0, 0); dv1 = __shfl(dv1, 0); dv2 = __shfl(dv2, 0);
        if (f < 3){
            float dvl = (f == 0) ? dv0 : (f == 1 ? dv1 : dv2);
            float vn = dvl + vscale * ldv<T>(A.v, bi*3 + f);
            float xn = ldv<T>(A.x, bi*3 + f) + vn;
            stv<T>(out, 32768 + bi*3 + f, xn);  // x_new
            stv<T>(out, 34304 + bi*3 + f, vn);  // v_new
        }
    }
}

extern "C" void kernel_launch(void* const* d_in, const int* in_sizes, int n_in,
                              void* d_out, int out_size, void* d_ws, size_t ws_size,
                              hipStream_t stream)
{
    Args A;
    A.h     = d_in[0];  A.x     = d_in[1];  A.v     = d_in[2];
    A.Win   = d_in[3];  A.bin   = d_in[4];  A.means = d_in[5];  A.betas = d_in[6];
    A.Wo1   = d_in[7];  A.bo1   = d_in[8];  A.Wo2   = d_in[9];  A.bo2   = d_in[10];
    A.Wsem  = d_in[11]; A.bsem  = d_in[12]; A.Wx    = d_in[13];
    A.Wp1   = d_in[14]; A.bp1   = d_in[15]; A.Wp2   = d_in[16]; A.bp2   = d_in[17];
    A.Wn1   = d_in[18]; A.bn1   = d_in[19]; A.Wn2   = d_in[20]; A.bn2   = d_in[21];
    A.Wv1   = d_in[22]; A.bv1   = d_in[23]; A.Wv2   = d_in[24]; A.Wvm   = d_in[25];

    int* flag = (int*)d_ws;
    k_detect<<<1, 64, 0, stream>>>(A.means, flag);
    k_sake<bf16,  0><<<NNODE, 256, 0, stream>>>(A, flag, d_out);
    k_sake<float, 1><<<NNODE, 256, 0, stream>>>(A, flag, d_out);
}

// Round 13
// 333.895 us; speedup vs baseline: 3.9799x; 3.3753x over previous
//
#include <hip/hip_runtime.h>
#include <hip/hip_bf16.h>

typedef __hip_bfloat16 bf16;
typedef __attribute__((ext_vector_type(8))) short bf16x8;
typedef __attribute__((ext_vector_type(4))) float f32x4;

#define NNODE 512   // B*N

__device__ __forceinline__ float b2f(bf16 v){ return __bfloat162float(v); }
__device__ __forceinline__ float siluf(float x){ return x / (1.f + __expf(-x)); }
__device__ __forceinline__ float tanhfast(float x){ return 1.f - 2.f/(__expf(2.f*x)+1.f); }
__device__ __forceinline__ float celu2(float x){ return x > 0.f ? x : 2.f*(__expf(0.5f*x)-1.f); }
__device__ __forceinline__ float bs2f(short v){ union{unsigned int i; float f;} t; t.i = ((unsigned int)(unsigned short)v) << 16; return t.f; }
__device__ __forceinline__ short f2bs(float x){ union{ bf16 b; short s; } u; u.b = __float2bfloat16(x); return u.s; }

// ---- dtype-polymorphic scalar load/store -------------------------------------------
template<typename T> __device__ __forceinline__ float ldv(const void* p, int i);
template<> __device__ __forceinline__ float ldv<float>(const void* p, int i){ return ((const float*)p)[i]; }
template<> __device__ __forceinline__ float ldv<bf16 >(const void* p, int i){ return b2f(((const bf16*)p)[i]); }

template<typename T> __device__ __forceinline__ void stv(void* p, int i, float v);
template<> __device__ __forceinline__ void stv<float>(void* p, int i, float v){ ((float*)p)[i] = v; }
template<> __device__ __forceinline__ void stv<bf16 >(void* p, int i, float v){ ((bf16*)p)[i] = __float2bfloat16(v); }

// load one element as bf16 bit-pattern (short)
template<typename T> __device__ __forceinline__ short ldbs(const void* p, int i);
template<> __device__ __forceinline__ short ldbs<bf16 >(const void* p, int i){ union{ bf16 b; short s; } u; u.b = ((const bf16*)p)[i]; return u.s; }
template<> __device__ __forceinline__ short ldbs<float>(const void* p, int i){ return f2bs(((const float*)p)[i]); }

struct Args {
    const void *h,*x,*v,*Win,*bin,*means,*betas,*Wo1,*bo1,*Wo2,*bo2,*Wsem,*bsem,*Wx,
               *Wp1,*bp1,*Wp2,*bp2,*Wn1,*bn1,*Wn2,*bn2,*Wv1,*bv1,*Wv2,*Wvm;
};

// ---- dtype detector: rbf_means[0] ~ 0.0067; read as bf16 low-half of an f32 it is huge
__global__ void k_detect(const void* means, int* flag){
    if (threadIdx.x == 0){
        float v = b2f(((const bf16*)means)[0]);
        flag[0] = (fabsf(v) > 1.0f || v != v) ? 1 : 0;   // 1 => inputs are float32
    }
}

// ---- per-node precompute: U1[j] = h_j @ Wo1[0:64], Aj[j] = h_j @ Win[0:64] ---------
// These are i-independent; every i-block previously recomputed them for all 256 j.
template<typename T, int WANT>
__global__ void __launch_bounds__(64) k_nodepre(Args A, const int* __restrict__ flag,
                                                float* __restrict__ U1, float* __restrict__ Aj)
{
    if (flag[0] != WANT) return;
    int bn = blockIdx.x, t = threadIdx.x;
    __shared__ float sh[64];
    sh[t] = ldv<T>(A.h, bn*64 + t);
    __syncthreads();
    float u1 = 0.f;
    for (int f = 0; f < 64; ++f) u1 += sh[f] * ldv<T>(A.Wo1, f*64 + t);
    U1[bn*64 + t] = u1;
    if (t < 50){
        float a1 = 0.f;
        for (int f = 0; f < 64; ++f) a1 += sh[f] * ldv<T>(A.Win, f*50 + t);
        Aj[bn*64 + t] = a1;
    }
}

// ---- fused SAKE layer: one block per (b,i) node; 256 threads (4 waves) -------------
// R12 base with edge phase restructured: U1/Aj read from global precompute (replaces
// the two 64-iteration per-pass loops), s_h staging dropped, and the 4-per-pass
// barriers removed (s_rbfh/s_mid are per-wave scratch; s_e/s_x4 only read after the
// loop -> ONE barrier after the edge loop).
template<typename T, int WANT>
__global__ void __launch_bounds__(256) k_sake(Args A, const int* __restrict__ flag,
                                              const float* __restrict__ U1w,
                                              const float* __restrict__ Ajw,
                                              void* __restrict__ out)
{
    if (flag[0] != WANT) return;

    int bi = blockIdx.x;
    int b = bi >> 8, i = bi & 255;
    int tid = threadIdx.x, w = tid >> 6, lane = tid & 63;

    __shared__ float s_hi[64];           // h_i                          256 B
    __shared__ bf16  s_e[256][66];       // edge features (row padded)  33.8 KB
    __shared__ float s_att[256][4];      // logits -> softmax weights      4 KB
    __shared__ float s_x4[256][4];       // xhat[3], d                     4 KB
    __shared__ float s_rbfh[4][4][52];   // per-wave scratch             3.3 KB
    __shared__ float s_mid[4][4][64];    // per-wave scratch               4 KB
    __shared__ float s_sm[1024];         // softmax scratch                4 KB
    __shared__ float s_red[768];         // comb_sum result                3 KB
    __shared__ float s_he[256];          // h_e                            1 KB
    __shared__ float s_cn[256];          // comb_norm                      1 KB
    __shared__ float s_f1[64], s_f2[64], s_f3[64], s_f4[64];  //           1 KB

    s_red[tid] = 0.f; s_red[tid+256] = 0.f; s_red[tid+512] = 0.f;
    if (tid < 64) s_hi[tid] = ldv<T>(A.h, bi*64 + tid);
    __syncthreads();

    float xi0 = ldv<T>(A.x, bi*3+0), xi1 = ldv<T>(A.x, bi*3+1), xi2 = ldv<T>(A.x, bi*3+2);

    // per-lane i-side constants
    float bo1v  = ldv<T>(A.bo1, lane);
    float wlast = ldv<T>(A.Wo1, 178*64 + lane);
    float bo2v  = ldv<T>(A.bo2, lane);
    float u2v = 0.f;
    for (int f = 0; f < 64; ++f) u2v += s_hi[f] * ldv<T>(A.Wo1, (64+f)*64 + lane);
    float muv = 0.f, bev = 0.f, binv = 0.f, aiv = 0.f;
    if (lane < 50){
        muv = ldv<T>(A.means, lane); bev = ldv<T>(A.betas, lane); binv = ldv<T>(A.bin, lane);
        for (int f = 0; f < 64; ++f) aiv += s_hi[f] * ldv<T>(A.Win, (64+f)*50 + lane);
    }

    // ================= edge phase: 16 passes x (4 waves x 4 pairs) =================
    // no in-pass barriers: s_rbfh/s_mid indexed by own wave w; s_e/s_x4 read after loop
    for (int pass = 0; pass < 16; ++pass){
        int j0 = pass*16 + w*4;
        float dist[4];
        #pragma unroll
        for (int pp = 0; pp < 4; ++pp){
            int j = j0 + pp;
            float dx = ldv<T>(A.x,(b*256+j)*3+0) - xi0;
            float dy = ldv<T>(A.x,(b*256+j)*3+1) - xi1;
            float dz = ldv<T>(A.x,(b*256+j)*3+2) - xi2;
            float dd = sqrtf(dx*dx + dy*dy + dz*dz + 1e-5f);
            dist[pp] = dd;
            if (lane == 0){
                float inv = 1.f/(dd + 1e-5f);
                s_x4[j][0] = dx*inv; s_x4[j][1] = dy*inv; s_x4[j][2] = dz*inv; s_x4[j][3] = dd;
            }
        }
        if (lane < 50){
            #pragma unroll
            for (int pp = 0; pp < 4; ++pp){
                int j = j0 + pp;
                float h1 = Ajw[(b*256+j)*64 + lane] + aiv + binv;
                float dd = dist[pp];
                float cut = (dd < 5.f) ? 0.5f*(__cosf(dd*0.6283185307f) + 1.f) : 0.f;
                float ex = __expf(-dd) - muv;
                s_rbfh[w][pp][lane] = cut * __expf(-bev*ex*ex) * h1;
            }
        }

        // o1 = U1[j] (precomputed) + U2[i] + b_o1 + d*w_last + rbf*h1 part
        float acc[4];
        #pragma unroll
        for (int pp = 0; pp < 4; ++pp)
            acc[pp] = U1w[(b*256 + j0 + pp)*64 + lane] + u2v + bo1v + dist[pp]*wlast;
        for (int k = 0; k < 50; ++k){
            float wv = ldv<T>(A.Wo1, (128+k)*64 + lane);
            #pragma unroll
            for (int pp = 0; pp < 4; ++pp) acc[pp] += s_rbfh[w][pp][k] * wv;
        }
        #pragma unroll
        for (int pp = 0; pp < 4; ++pp) s_mid[w][pp][lane] = siluf(acc[pp]);

        // o2
        float acc2[4] = {bo2v, bo2v, bo2v, bo2v};
        for (int k = 0; k < 64; ++k){
            float wv = ldv<T>(A.Wo2, k*64 + lane);
            #pragma unroll
            for (int pp = 0; pp < 4; ++pp) acc2[pp] += s_mid[w][pp][k] * wv;
        }
        #pragma unroll
        for (int pp = 0; pp < 4; ++pp) s_e[j0+pp][lane] = __float2bfloat16(acc2[pp]);
    }
    __syncthreads();   // single barrier: s_e / s_x4 now visible to all waves

    // ================= semantic attention logits (thread = j) =================
    {
        int j = tid;
        float a0 = ldv<T>(A.bsem,0), a1 = ldv<T>(A.bsem,1), a2 = ldv<T>(A.bsem,2), a3 = ldv<T>(A.bsem,3);
        for (int f = 0; f < 64; ++f){
            float ev = b2f(s_e[j][f]);
            a0 += ev * ldv<T>(A.Wsem, f*4+0);
            a1 += ev * ldv<T>(A.Wsem, f*4+1);
            a2 += ev * ldv<T>(A.Wsem, f*4+2);
            a3 += ev * ldv<T>(A.Wsem, f*4+3);
        }
        a0 = celu2(a0); a1 = celu2(a1); a2 = celu2(a2); a3 = celu2(a3);
        if (j == i){ a0 -= 1e5f; a1 -= 1e5f; a2 -= 1e5f; a3 -= 1e5f; }
        s_att[j][0] = a0; s_att[j][1] = a1; s_att[j][2] = a2; s_att[j][3] = a3;
    }
    __syncthreads();

    // ================= softmax over j (4 heads) =================
    {
        float l0 = s_att[tid][0], l1 = s_att[tid][1], l2 = s_att[tid][2], l3 = s_att[tid][3];
        s_sm[tid*4+0]=l0; s_sm[tid*4+1]=l1; s_sm[tid*4+2]=l2; s_sm[tid*4+3]=l3;
        __syncthreads();
        for (int off = 128; off > 0; off >>= 1){
            if (tid < off){
                s_sm[tid*4+0] = fmaxf(s_sm[tid*4+0], s_sm[(tid+off)*4+0]);
                s_sm[tid*4+1] = fmaxf(s_sm[tid*4+1], s_sm[(tid+off)*4+1]);
                s_sm[tid*4+2] = fmaxf(s_sm[tid*4+2], s_sm[(tid+off)*4+2]);
                s_sm[tid*4+3] = fmaxf(s_sm[tid*4+3], s_sm[(tid+off)*4+3]);
            }
            __syncthreads();
        }
        float m0 = s_sm[0], m1 = s_sm[1], m2 = s_sm[2], m3 = s_sm[3];
        __syncthreads();
        float e0 = __expf(l0-m0), e1 = __expf(l1-m1), e2 = __expf(l2-m2), e3 = __expf(l3-m3);
        s_sm[tid*4+0]=e0; s_sm[tid*4+1]=e1; s_sm[tid*4+2]=e2; s_sm[tid*4+3]=e3;
        __syncthreads();
        for (int off = 128; off > 0; off >>= 1){
            if (tid < off){
                s_sm[tid*4+0] += s_sm[(tid+off)*4+0];
                s_sm[tid*4+1] += s_sm[(tid+off)*4+1];
                s_sm[tid*4+2] += s_sm[(tid+off)*4+2];
                s_sm[tid*4+3] += s_sm[(tid+off)*4+3];
            }
            __syncthreads();
        }
        s_att[tid][0] = e0 / s_sm[0];
        s_att[tid][1] = e1 / s_sm[1];
        s_att[tid][2] = e2 / s_sm[2];
        s_att[tid][3] = e3 / s_sm[3];
    }
    __syncthreads();

    // ================= h_e[c] = sum_j e[j][f]*att[j][h], c = 4f+h =================
    {
        int f_he = tid >> 2, h_he = tid & 3;
        float he_acc = 0.f;
        for (int j2 = 0; j2 < 256; ++j2)
            he_acc += b2f(s_e[j2][f_he]) * s_att[j2][h_he];
        s_he[tid] = he_acc;
    }

    // ================= x-mixing via MFMA: P = A @ Wx, A[j,4f+h]=e[j][f]*att[j][h] ====
    // wave w owns c-slice [w*64, w*64+64), processed as TWO sequential 32-column halves
    {
        int lane15 = lane & 15, quad = lane >> 4;
        const short* se_s = (const short*)s_e;   // s_e[j][f] -> se_s[j*66+f]

        for (int chalf = 0; chalf < 2; ++chalf){
            int n0 = w*64 + chalf*32;
            float comb_acc[2][3];
            #pragma unroll
            for (int nf = 0; nf < 2; ++nf){ comb_acc[nf][0]=0.f; comb_acc[nf][1]=0.f; comb_acc[nf][2]=0.f; }

            for (int jt = 0; jt < 4; ++jt){
                int jbase = jt*64;
                f32x4 Cc[4][2];
                #pragma unroll
                for (int mf = 0; mf < 4; ++mf)
                    #pragma unroll
                    for (int nf = 0; nf < 2; ++nf)
                        Cc[mf][nf] = (f32x4){0.f, 0.f, 0.f, 0.f};

                float am[4][4];
                #pragma unroll
                for (int mf = 0; mf < 4; ++mf){
                    int jr = jbase + mf*16 + lane15;
                    am[mf][0] = s_att[jr][0]; am[mf][1] = s_att[jr][1];
                    am[mf][2] = s_att[jr][2]; am[mf][3] = s_att[jr][3];
                }

                for (int kk = 0; kk < 8; ++kk){
                    bf16x8 Bf[2];
                    #pragma unroll
                    for (int nf = 0; nf < 2; ++nf){
                        int n = n0 + nf*16 + lane15;
                        int kb = (kk*32 + quad*8)*256 + n;
                        bf16x8 bv;
                        #pragma unroll
                        for (int t = 0; t < 8; ++t) bv[t] = ldbs<T>(A.Wx, kb + t*256);
                        Bf[nf] = bv;
                    }
                    int f0 = kk*8 + quad*2;
                    bf16x8 Af[4];
                    #pragma unroll
                    for (int mf = 0; mf < 4; ++mf){
                        int jr = jbase + mf*16 + lane15;
                        float e0 = bs2f(se_s[jr*66 + f0]);
                        float e1 = bs2f(se_s[jr*66 + f0 + 1]);
                        bf16x8 av;
                        av[0]=f2bs(e0*am[mf][0]); av[1]=f2bs(e0*am[mf][1]);
                        av[2]=f2bs(e0*am[mf][2]); av[3]=f2bs(e0*am[mf][3]);
                        av[4]=f2bs(e1*am[mf][0]); av[5]=f2bs(e1*am[mf][1]);
                        av[6]=f2bs(e1*am[mf][2]); av[7]=f2bs(e1*am[mf][3]);
                        Af[mf] = av;
                    }
                    #pragma unroll
                    for (int mf = 0; mf < 4; ++mf)
                        #pragma unroll
                        for (int nf = 0; nf < 2; ++nf)
                            Cc[mf][nf] = __builtin_amdgcn_mfma_f32_16x16x32_bf16(Af[mf], Bf[nf], Cc[mf][nf], 0, 0, 0);
                }

                #pragma unroll
                for (int mf = 0; mf < 4; ++mf){
                    #pragma unroll
                    for (int r = 0; r < 4; ++r){
                        int j = jbase + mf*16 + quad*4 + r;
                        float x0 = s_x4[j][0], x1 = s_x4[j][1], x2 = s_x4[j][2];
                        #pragma unroll
                        for (int nf = 0; nf < 2; ++nf){
                            float cf = tanhfast(Cc[mf][nf][r]);
                            comb_acc[nf][0] += cf*x0;
                            comb_acc[nf][1] += cf*x1;
                            comb_acc[nf][2] += cf*x2;
                        }
                    }
                }
            }

            #pragma unroll
            for (int nf = 0; nf < 2; ++nf){
                #pragma unroll
                for (int d = 0; d < 3; ++d){
                    float vsum = comb_acc[nf][d];
                    vsum += __shfl_xor(vsum, 16);
                    vsum += __shfl_xor(vsum, 32);
                    if (quad == 0) s_red[(n0 + nf*16 + lane15)*3 + d] = vsum;
                }
            }
        }
    }
    __syncthreads();

    // ================= final per-node MLPs =================
    const float sc = 1.f/256.f;
    {
        float cb0 = s_red[tid*3+0]*sc, cb1 = s_red[tid*3+1]*sc, cb2 = s_red[tid*3+2]*sc;
        s_cn[tid] = cb0*cb0 + cb1*cb1 + cb2*cb2;
    }
    __syncthreads();

    if (tid < 64){
        int f = tid;
        float acc = ldv<T>(A.bp1, f);
        for (int c = 0; c < 256; ++c) acc += s_cn[c] * ldv<T>(A.Wp1, c*64 + f);
        s_f1[f] = siluf(acc);
    }
    __syncthreads();
    if (tid < 64){
        int f = tid;
        float acc = ldv<T>(A.bp2, f);
        for (int k = 0; k < 64; ++k) acc += s_f1[k] * ldv<T>(A.Wp2, k*64 + f);
        s_f2[f] = siluf(acc);
    }
    __syncthreads();
    if (tid < 64){
        int f = tid;
        float acc = ldv<T>(A.bn1, f);
        for (int r = 0; r < 64; ++r)  acc += s_hi[r] * ldv<T>(A.Wn1, r*64 + f);
        for (int r = 0; r < 256; ++r) acc += s_he[r] * ldv<T>(A.Wn1, (64+r)*64 + f);
        for (int r = 0; r < 64; ++r)  acc += s_f2[r] * ldv<T>(A.Wn1, (320+r)*64 + f);
        s_f3[f] = siluf(acc);
    }
    __syncthreads();
    if (tid < 64){
        int f = tid;
        float acc = ldv<T>(A.bn2, f);
        for (int k = 0; k < 64; ++k) acc += s_f3[k] * ldv<T>(A.Wn2, k*64 + f);
        float hn = s_hi[f] + siluf(acc);
        stv<T>(out, bi*64 + f, hn);
        s_f4[f] = hn;
    }
    __syncthreads();
    if (tid < 64){
        int f = tid;
        float acc = ldv<T>(A.bv1, f);
        for (int k = 0; k < 64; ++k) acc += s_f4[k] * ldv<T>(A.Wv1, k*64 + f);
        float term = siluf(acc) * ldv<T>(A.Wv2, f);
        #pragma unroll
        for (int off = 32; off > 0; off >>= 1) term += __shfl_down(term, off);
        float vscale = 2.f / (1.f + __expf(-__shfl(term, 0)));

        float dv0 = 0.f, dv1 = 0.f, dv2 = 0.f;
        #pragma unroll
        for (int q = 0; q < 4; ++q){
            int c = q*64 + f;
            float wv = ldv<T>(A.Wvm, c);
            dv0 += s_red[c*3+0]*sc*wv;
            dv1 += s_red[c*3+1]*sc*wv;
            dv2 += s_red[c*3+2]*sc*wv;
        }
        #pragma unroll
        for (int off = 32; off > 0; off >>= 1){
            dv0 += __shfl_down(dv0, off);
            dv1 += __shfl_down(dv1, off);
            dv2 += __shfl_down(dv2, off);
        }
        dv0 = __shfl(dv0, 0); dv1 = __shfl(dv1, 0); dv2 = __shfl(dv2, 0);
        if (f < 3){
            float dvl = (f == 0) ? dv0 : (f == 1 ? dv1 : dv2);
            float vn = dvl + vscale * ldv<T>(A.v, bi*3 + f);
            float xn = ldv<T>(A.x, bi*3 + f) + vn;
            stv<T>(out, 32768 + bi*3 + f, xn);  // x_new
            stv<T>(out, 34304 + bi*3 + f, vn);  // v_new
        }
    }
}

extern "C" void kernel_launch(void* const* d_in, const int* in_sizes, int n_in,
                              void* d_out, int out_size, void* d_ws, size_t ws_size,
                              hipStream_t stream)
{
    Args A;
    A.h     = d_in[0];  A.x     = d_in[1];  A.v     = d_in[2];
    A.Win   = d_in[3];  A.bin   = d_in[4];  A.means = d_in[5];  A.betas = d_in[6];
    A.Wo1   = d_in[7];  A.bo1   = d_in[8];  A.Wo2   = d_in[9];  A.bo2   = d_in[10];
    A.Wsem  = d_in[11]; A.bsem  = d_in[12]; A.Wx    = d_in[13];
    A.Wp1   = d_in[14]; A.bp1   = d_in[15]; A.Wp2   = d_in[16]; A.bp2   = d_in[17];
    A.Wn1   = d_in[18]; A.bn1   = d_in[19]; A.Wn2   = d_in[20]; A.bn2   = d_in[21];
    A.Wv1   = d_in[22]; A.bv1   = d_in[23]; A.Wv2   = d_in[24]; A.Wvm   = d_in[25];

    // ws layout: [0:16) floats = flag area; U1 = 512x64 f32; Aj = 512x64 f32 (~262 KB)
    float* wsf = (float*)d_ws;
    int*   flag = (int*)d_ws;
    float* U1 = wsf + 16;
    float* Aj = U1 + 32768;

    k_detect<<<1, 64, 0, stream>>>(A.means, flag);
    k_nodepre<bf16,  0><<<NNODE, 64, 0, stream>>>(A, flag, U1, Aj);
    k_nodepre<float, 1><<<NNODE, 64, 0, stream>>>(A, flag, U1, Aj);
    k_sake<bf16,  0><<<NNODE, 256, 0, stream>>>(A, flag, U1, Aj, d_out);
    k_sake<float, 1><<<NNODE, 256, 0, stream>>>(A, flag, U1, Aj, d_out);
}

// Round 14
// 314.718 us; speedup vs baseline: 4.2225x; 1.0609x over previous
//
#include <hip/hip_runtime.h>
#include <hip/hip_bf16.h>

typedef __hip_bfloat16 bf16;
typedef __attribute__((ext_vector_type(8))) short bf16x8;
typedef __attribute__((ext_vector_type(4))) float f32x4;

#define NNODE 512   // B*N

__device__ __forceinline__ float b2f(bf16 v){ return __bfloat162float(v); }
__device__ __forceinline__ float siluf(float x){ return x / (1.f + __expf(-x)); }
__device__ __forceinline__ float tanhfast(float x){ return 1.f - 2.f/(__expf(2.f*x)+1.f); }
__device__ __forceinline__ float celu2(float x){ return x > 0.f ? x : 2.f*(__expf(0.5f*x)-1.f); }
__device__ __forceinline__ float bs2f(short v){ union{unsigned int i; float f;} t; t.i = ((unsigned int)(unsigned short)v) << 16; return t.f; }
__device__ __forceinline__ short f2bs(float x){ union{ bf16 b; short s; } u; u.b = __float2bfloat16(x); return u.s; }

// ---- dtype-polymorphic scalar load/store -------------------------------------------
template<typename T> __device__ __forceinline__ float ldv(const void* p, int i);
template<> __device__ __forceinline__ float ldv<float>(const void* p, int i){ return ((const float*)p)[i]; }
template<> __device__ __forceinline__ float ldv<bf16 >(const void* p, int i){ return b2f(((const bf16*)p)[i]); }

template<typename T> __device__ __forceinline__ void stv(void* p, int i, float v);
template<> __device__ __forceinline__ void stv<float>(void* p, int i, float v){ ((float*)p)[i] = v; }
template<> __device__ __forceinline__ void stv<bf16 >(void* p, int i, float v){ ((bf16*)p)[i] = __float2bfloat16(v); }

// load one element as bf16 bit-pattern (short)
template<typename T> __device__ __forceinline__ short ldbs(const void* p, int i);
template<> __device__ __forceinline__ short ldbs<bf16 >(const void* p, int i){ union{ bf16 b; short s; } u; u.b = ((const bf16*)p)[i]; return u.s; }
template<> __device__ __forceinline__ short ldbs<float>(const void* p, int i){ return f2bs(((const float*)p)[i]); }

struct Args {
    const void *h,*x,*v,*Win,*bin,*means,*betas,*Wo1,*bo1,*Wo2,*bo2,*Wsem,*bsem,*Wx,
               *Wp1,*bp1,*Wp2,*bp2,*Wn1,*bn1,*Wn2,*bn2,*Wv1,*bv1,*Wv2,*Wvm;
};

// ---- dtype detector: rbf_means[0] ~ 0.0067; read as bf16 low-half of an f32 it is huge
__global__ void k_detect(const void* means, int* flag){
    if (threadIdx.x == 0){
        float v = b2f(((const bf16*)means)[0]);
        flag[0] = (fabsf(v) > 1.0f || v != v) ? 1 : 0;   // 1 => inputs are float32
    }
}

// ---- per-node precompute: U1[j] = h_j @ Wo1[0:64], Aj[j] = h_j @ Win[0:64] ---------
// Also transposes Wx -> WxT[n][k] (bf16) so mixing B-fragments become one 16B load.
template<typename T, int WANT>
__global__ void __launch_bounds__(64) k_nodepre(Args A, const int* __restrict__ flag,
                                                float* __restrict__ U1, float* __restrict__ Aj,
                                                short* __restrict__ WxT)
{
    if (flag[0] != WANT) return;
    int bn = blockIdx.x, t = threadIdx.x;
    __shared__ float sh[64];
    sh[t] = ldv<T>(A.h, bn*64 + t);
    __syncthreads();
    float u1 = 0.f;
    for (int f = 0; f < 64; ++f) u1 += sh[f] * ldv<T>(A.Wo1, f*64 + t);
    U1[bn*64 + t] = u1;
    if (t < 50){
        float a1 = 0.f;
        for (int f = 0; f < 64; ++f) a1 += sh[f] * ldv<T>(A.Win, f*50 + t);
        Aj[bn*64 + t] = a1;
    }
    // transpose Wx (2 elements per thread across the grid)
    int g = bn*64 + t;            // 0..32767
    int e0 = g*2;
    int n = e0 >> 8, k = e0 & 255;
    WxT[n*256 + k]     = ldbs<T>(A.Wx, k*256 + n);
    WxT[n*256 + k + 1] = ldbs<T>(A.Wx, (k+1)*256 + n);
}

// ---- fused SAKE layer: one block per (b,i) node; 256 threads (4 waves) -------------
// R13 base (334us) + (1) mixing B-frags from transposed WxT via single 16B loads,
// (2) Wo2 + Wo1-rbf rows staged in LDS once per block (edge weight reads go
// global->LDS; 2 lanes/bank = conflict-free).
template<typename T, int WANT>
__global__ void __launch_bounds__(256) k_sake(Args A, const int* __restrict__ flag,
                                              const float* __restrict__ U1w,
                                              const float* __restrict__ Ajw,
                                              const short* __restrict__ wxt,
                                              void* __restrict__ out)
{
    if (flag[0] != WANT) return;

    int bi = blockIdx.x;
    int b = bi >> 8, i = bi & 255;
    int tid = threadIdx.x, w = tid >> 6, lane = tid & 63;

    __shared__ float s_hi[64];           // h_i                          256 B
    __shared__ bf16  s_e[256][66];       // edge features (row padded)  33.8 KB
    __shared__ float s_att[256][4];      // logits -> softmax weights      4 KB
    __shared__ float s_x4[256][4];       // xhat[3], d                     4 KB
    __shared__ float s_rbfh[4][4][52];   // per-wave scratch             3.3 KB
    __shared__ float s_mid[4][4][64];    // per-wave scratch               4 KB
    __shared__ float s_sm[1024];         // softmax scratch                4 KB
    __shared__ float s_red[768];         // comb_sum result                3 KB
    __shared__ float s_he[256];          // h_e                            1 KB
    __shared__ float s_cn[256];          // comb_norm                      1 KB
    __shared__ float s_f1[64], s_f2[64], s_f3[64], s_f4[64];  //           1 KB
    __shared__ short s_wo2[4096];        // Wo2 staged bf16                8 KB
    __shared__ short s_wo1r[3200];       // Wo1 rows 128..177 staged    6.25 KB

    s_red[tid] = 0.f; s_red[tid+256] = 0.f; s_red[tid+512] = 0.f;
    if (tid < 64) s_hi[tid] = ldv<T>(A.h, bi*64 + tid);
    // stage Wo2 (4096) and Wo1 rbf rows (3200) into LDS
    #pragma unroll
    for (int q = 0; q < 16; ++q){
        int idx = q*256 + tid;
        s_wo2[idx] = ldbs<T>(A.Wo2, idx);
    }
    #pragma unroll
    for (int q = 0; q < 13; ++q){
        int idx = q*256 + tid;
        if (idx < 3200) s_wo1r[idx] = ldbs<T>(A.Wo1, (128 + (idx>>6))*64 + (idx&63));
    }
    __syncthreads();

    float xi0 = ldv<T>(A.x, bi*3+0), xi1 = ldv<T>(A.x, bi*3+1), xi2 = ldv<T>(A.x, bi*3+2);

    // per-lane i-side constants
    float bo1v  = ldv<T>(A.bo1, lane);
    float wlast = ldv<T>(A.Wo1, 178*64 + lane);
    float bo2v  = ldv<T>(A.bo2, lane);
    float u2v = 0.f;
    for (int f = 0; f < 64; ++f) u2v += s_hi[f] * ldv<T>(A.Wo1, (64+f)*64 + lane);
    float muv = 0.f, bev = 0.f, binv = 0.f, aiv = 0.f;
    if (lane < 50){
        muv = ldv<T>(A.means, lane); bev = ldv<T>(A.betas, lane); binv = ldv<T>(A.bin, lane);
        for (int f = 0; f < 64; ++f) aiv += s_hi[f] * ldv<T>(A.Win, (64+f)*50 + lane);
    }

    // ================= edge phase: 16 passes x (4 waves x 4 pairs) =================
    // no in-pass barriers: s_rbfh/s_mid indexed by own wave w; s_e/s_x4 read after loop
    for (int pass = 0; pass < 16; ++pass){
        int j0 = pass*16 + w*4;
        float dist[4];
        #pragma unroll
        for (int pp = 0; pp < 4; ++pp){
            int j = j0 + pp;
            float dx = ldv<T>(A.x,(b*256+j)*3+0) - xi0;
            float dy = ldv<T>(A.x,(b*256+j)*3+1) - xi1;
            float dz = ldv<T>(A.x,(b*256+j)*3+2) - xi2;
            float dd = sqrtf(dx*dx + dy*dy + dz*dz + 1e-5f);
            dist[pp] = dd;
            if (lane == 0){
                float inv = 1.f/(dd + 1e-5f);
                s_x4[j][0] = dx*inv; s_x4[j][1] = dy*inv; s_x4[j][2] = dz*inv; s_x4[j][3] = dd;
            }
        }
        if (lane < 50){
            #pragma unroll
            for (int pp = 0; pp < 4; ++pp){
                int j = j0 + pp;
                float h1 = Ajw[(b*256+j)*64 + lane] + aiv + binv;
                float dd = dist[pp];
                float cut = (dd < 5.f) ? 0.5f*(__cosf(dd*0.6283185307f) + 1.f) : 0.f;
                float ex = __expf(-dd) - muv;
                s_rbfh[w][pp][lane] = cut * __expf(-bev*ex*ex) * h1;
            }
        }

        // o1 = U1[j] (precomputed) + U2[i] + b_o1 + d*w_last + rbf*h1 part (LDS weights)
        float acc[4];
        #pragma unroll
        for (int pp = 0; pp < 4; ++pp)
            acc[pp] = U1w[(b*256 + j0 + pp)*64 + lane] + u2v + bo1v + dist[pp]*wlast;
        for (int k = 0; k < 50; ++k){
            float wv = bs2f(s_wo1r[k*64 + lane]);
            #pragma unroll
            for (int pp = 0; pp < 4; ++pp) acc[pp] += s_rbfh[w][pp][k] * wv;
        }
        #pragma unroll
        for (int pp = 0; pp < 4; ++pp) s_mid[w][pp][lane] = siluf(acc[pp]);

        // o2 (LDS weights)
        float acc2[4] = {bo2v, bo2v, bo2v, bo2v};
        for (int k = 0; k < 64; ++k){
            float wv = bs2f(s_wo2[k*64 + lane]);
            #pragma unroll
            for (int pp = 0; pp < 4; ++pp) acc2[pp] += s_mid[w][pp][k] * wv;
        }
        #pragma unroll
        for (int pp = 0; pp < 4; ++pp) s_e[j0+pp][lane] = __float2bfloat16(acc2[pp]);
    }
    __syncthreads();   // single barrier: s_e / s_x4 now visible to all waves

    // ================= semantic attention logits (thread = j) =================
    {
        int j = tid;
        float a0 = ldv<T>(A.bsem,0), a1 = ldv<T>(A.bsem,1), a2 = ldv<T>(A.bsem,2), a3 = ldv<T>(A.bsem,3);
        for (int f = 0; f < 64; ++f){
            float ev = b2f(s_e[j][f]);
            a0 += ev * ldv<T>(A.Wsem, f*4+0);
            a1 += ev * ldv<T>(A.Wsem, f*4+1);
            a2 += ev * ldv<T>(A.Wsem, f*4+2);
            a3 += ev * ldv<T>(A.Wsem, f*4+3);
        }
        a0 = celu2(a0); a1 = celu2(a1); a2 = celu2(a2); a3 = celu2(a3);
        if (j == i){ a0 -= 1e5f; a1 -= 1e5f; a2 -= 1e5f; a3 -= 1e5f; }
        s_att[j][0] = a0; s_att[j][1] = a1; s_att[j][2] = a2; s_att[j][3] = a3;
    }
    __syncthreads();

    // ================= softmax over j (4 heads) =================
    {
        float l0 = s_att[tid][0], l1 = s_att[tid][1], l2 = s_att[tid][2], l3 = s_att[tid][3];
        s_sm[tid*4+0]=l0; s_sm[tid*4+1]=l1; s_sm[tid*4+2]=l2; s_sm[tid*4+3]=l3;
        __syncthreads();
        for (int off = 128; off > 0; off >>= 1){
            if (tid < off){
                s_sm[tid*4+0] = fmaxf(s_sm[tid*4+0], s_sm[(tid+off)*4+0]);
                s_sm[tid*4+1] = fmaxf(s_sm[tid*4+1], s_sm[(tid+off)*4+1]);
                s_sm[tid*4+2] = fmaxf(s_sm[tid*4+2], s_sm[(tid+off)*4+2]);
                s_sm[tid*4+3] = fmaxf(s_sm[tid*4+3], s_sm[(tid+off)*4+3]);
            }
            __syncthreads();
        }
        float m0 = s_sm[0], m1 = s_sm[1], m2 = s_sm[2], m3 = s_sm[3];
        __syncthreads();
        float e0 = __expf(l0-m0), e1 = __expf(l1-m1), e2 = __expf(l2-m2), e3 = __expf(l3-m3);
        s_sm[tid*4+0]=e0; s_sm[tid*4+1]=e1; s_sm[tid*4+2]=e2; s_sm[tid*4+3]=e3;
        __syncthreads();
        for (int off = 128; off > 0; off >>= 1){
            if (tid < off){
                s_sm[tid*4+0] += s_sm[(tid+off)*4+0];
                s_sm[tid*4+1] += s_sm[(tid+off)*4+1];
                s_sm[tid*4+2] += s_sm[(tid+off)*4+2];
                s_sm[tid*4+3] += s_sm[(tid+off)*4+3];
            }
            __syncthreads();
        }
        s_att[tid][0] = e0 / s_sm[0];
        s_att[tid][1] = e1 / s_sm[1];
        s_att[tid][2] = e2 / s_sm[2];
        s_att[tid][3] = e3 / s_sm[3];
    }
    __syncthreads();

    // ================= h_e[c] = sum_j e[j][f]*att[j][h], c = 4f+h =================
    {
        int f_he = tid >> 2, h_he = tid & 3;
        float he_acc = 0.f;
        for (int j2 = 0; j2 < 256; ++j2)
            he_acc += b2f(s_e[j2][f_he]) * s_att[j2][h_he];
        s_he[tid] = he_acc;
    }

    // ================= x-mixing via MFMA: P = A @ Wx, A[j,4f+h]=e[j][f]*att[j][h] ====
    // wave w owns c-slice [w*64, w*64+64), processed as TWO sequential 32-column halves
    {
        int lane15 = lane & 15, quad = lane >> 4;
        const short* se_s = (const short*)s_e;   // s_e[j][f] -> se_s[j*66+f]

        for (int chalf = 0; chalf < 2; ++chalf){
            int n0 = w*64 + chalf*32;
            float comb_acc[2][3];
            #pragma unroll
            for (int nf = 0; nf < 2; ++nf){ comb_acc[nf][0]=0.f; comb_acc[nf][1]=0.f; comb_acc[nf][2]=0.f; }

            for (int jt = 0; jt < 4; ++jt){
                int jbase = jt*64;
                f32x4 Cc[4][2];
                #pragma unroll
                for (int mf = 0; mf < 4; ++mf)
                    #pragma unroll
                    for (int nf = 0; nf < 2; ++nf)
                        Cc[mf][nf] = (f32x4){0.f, 0.f, 0.f, 0.f};

                float am[4][4];
                #pragma unroll
                for (int mf = 0; mf < 4; ++mf){
                    int jr = jbase + mf*16 + lane15;
                    am[mf][0] = s_att[jr][0]; am[mf][1] = s_att[jr][1];
                    am[mf][2] = s_att[jr][2]; am[mf][3] = s_att[jr][3];
                }

                for (int kk = 0; kk < 8; ++kk){
                    // B fragments: one aligned 16B load each from transposed WxT[n][k]
                    bf16x8 Bf[2];
                    #pragma unroll
                    for (int nf = 0; nf < 2; ++nf){
                        int n = n0 + nf*16 + lane15;
                        Bf[nf] = *(const bf16x8*)(wxt + n*256 + kk*32 + quad*8);
                    }
                    int f0 = kk*8 + quad*2;
                    bf16x8 Af[4];
                    #pragma unroll
                    for (int mf = 0; mf < 4; ++mf){
                        int jr = jbase + mf*16 + lane15;
                        float e0 = bs2f(se_s[jr*66 + f0]);
                        float e1 = bs2f(se_s[jr*66 + f0 + 1]);
                        bf16x8 av;
                        av[0]=f2bs(e0*am[mf][0]); av[1]=f2bs(e0*am[mf][1]);
                        av[2]=f2bs(e0*am[mf][2]); av[3]=f2bs(e0*am[mf][3]);
                        av[4]=f2bs(e1*am[mf][0]); av[5]=f2bs(e1*am[mf][1]);
                        av[6]=f2bs(e1*am[mf][2]); av[7]=f2bs(e1*am[mf][3]);
                        Af[mf] = av;
                    }
                    #pragma unroll
                    for (int mf = 0; mf < 4; ++mf)
                        #pragma unroll
                        for (int nf = 0; nf < 2; ++nf)
                            Cc[mf][nf] = __builtin_amdgcn_mfma_f32_16x16x32_bf16(Af[mf], Bf[nf], Cc[mf][nf], 0, 0, 0);
                }

                #pragma unroll
                for (int mf = 0; mf < 4; ++mf){
                    #pragma unroll
                    for (int r = 0; r < 4; ++r){
                        int j = jbase + mf*16 + quad*4 + r;
                        float x0 = s_x4[j][0], x1 = s_x4[j][1], x2 = s_x4[j][2];
                        #pragma unroll
                        for (int nf = 0; nf < 2; ++nf){
                            float cf = tanhfast(Cc[mf][nf][r]);
                            comb_acc[nf][0] += cf*x0;
                            comb_acc[nf][1] += cf*x1;
                            comb_acc[nf][2] += cf*x2;
                        }
                    }
                }
            }

            #pragma unroll
            for (int nf = 0; nf < 2; ++nf){
                #pragma unroll
                for (int d = 0; d < 3; ++d){
                    float vsum = comb_acc[nf][d];
                    vsum += __shfl_xor(vsum, 16);
                    vsum += __shfl_xor(vsum, 32);
                    if (quad == 0) s_red[(n0 + nf*16 + lane15)*3 + d] = vsum;
                }
            }
        }
    }
    __syncthreads();

    // ================= final per-node MLPs =================
    const float sc = 1.f/256.f;
    {
        float cb0 = s_red[tid*3+0]*sc, cb1 = s_red[tid*3+1]*sc, cb2 = s_red[tid*3+2]*sc;
        s_cn[tid] = cb0*cb0 + cb1*cb1 + cb2*cb2;
    }
    __syncthreads();

    if (tid < 64){
        int f = tid;
        float acc = ldv<T>(A.bp1, f);
        for (int c = 0; c < 256; ++c) acc += s_cn[c] * ldv<T>(A.Wp1, c*64 + f);
        s_f1[f] = siluf(acc);
    }
    __syncthreads();
    if (tid < 64){
        int f = tid;
        float acc = ldv<T>(A.bp2, f);
        for (int k = 0; k < 64; ++k) acc += s_f1[k] * ldv<T>(A.Wp2, k*64 + f);
        s_f2[f] = siluf(acc);
    }
    __syncthreads();
    if (tid < 64){
        int f = tid;
        float acc = ldv<T>(A.bn1, f);
        for (int r = 0; r < 64; ++r)  acc += s_hi[r] * ldv<T>(A.Wn1, r*64 + f);
        for (int r = 0; r < 256; ++r) acc += s_he[r] * ldv<T>(A.Wn1, (64+r)*64 + f);
        for (int r = 0; r < 64; ++r)  acc += s_f2[r] * ldv<T>(A.Wn1, (320+r)*64 + f);
        s_f3[f] = siluf(acc);
    }
    __syncthreads();
    if (tid < 64){
        int f = tid;
        float acc = ldv<T>(A.bn2, f);
        for (int k = 0; k < 64; ++k) acc += s_f3[k] * ldv<T>(A.Wn2, k*64 + f);
        float hn = s_hi[f] + siluf(acc);
        stv<T>(out, bi*64 + f, hn);
        s_f4[f] = hn;
    }
    __syncthreads();
    if (tid < 64){
        int f = tid;
        float acc = ldv<T>(A.bv1, f);
        for (int k = 0; k < 64; ++k) acc += s_f4[k] * ldv<T>(A.Wv1, k*64 + f);
        float term = siluf(acc) * ldv<T>(A.Wv2, f);
        #pragma unroll
        for (int off = 32; off > 0; off >>= 1) term += __shfl_down(term, off);
        float vscale = 2.f / (1.f + __expf(-__shfl(term, 0)));

        float dv0 = 0.f, dv1 = 0.f, dv2 = 0.f;
        #pragma unroll
        for (int q = 0; q < 4; ++q){
            int c = q*64 + f;
            float wv = ldv<T>(A.Wvm, c);
            dv0 += s_red[c*3+0]*sc*wv;
            dv1 += s_red[c*3+1]*sc*wv;
            dv2 += s_red[c*3+2]*sc*wv;
        }
        #pragma unroll
        for (int off = 32; off > 0; off >>= 1){
            dv0 += __shfl_down(dv0, off);
            dv1 += __shfl_down(dv1, off);
            dv2 += __shfl_down(dv2, off);
        }
        dv0 = __shfl(dv0, 0); dv1 = __shfl(dv1, 0); dv2 = __shfl(dv2, 0);
        if (f < 3){
            float dvl = (f == 0) ? dv0 : (f == 1 ? dv1 : dv2);
            float vn = dvl + vscale * ldv<T>(A.v, bi*3 + f);
            float xn = ldv<T>(A.x, bi*3 + f) + vn;
            stv<T>(out, 32768 + bi*3 + f, xn);  // x_new
            stv<T>(out, 34304 + bi*3 + f, vn);  // v_new
        }
    }
}

extern "C" void kernel_launch(void* const* d_in, const int* in_sizes, int n_in,
                              void* d_out, int out_size, void* d_ws, size_t ws_size,
                              hipStream_t stream)
{
    Args A;
    A.h     = d_in[0];  A.x     = d_in[1];  A.v     = d_in[2];
    A.Win   = d_in[3];  A.bin   = d_in[4];  A.means = d_in[5];  A.betas = d_in[6];
    A.Wo1   = d_in[7];  A.bo1   = d_in[8];  A.Wo2   = d_in[9];  A.bo2   = d_in[10];
    A.Wsem  = d_in[11]; A.bsem  = d_in[12]; A.Wx    = d_in[13];
    A.Wp1   = d_in[14]; A.bp1   = d_in[15]; A.Wp2   = d_in[16]; A.bp2   = d_in[17];
    A.Wn1   = d_in[18]; A.bn1   = d_in[19]; A.Wn2   = d_in[20]; A.bn2   = d_in[21];
    A.Wv1   = d_in[22]; A.bv1   = d_in[23]; A.Wv2   = d_in[24]; A.Wvm   = d_in[25];

    // ws layout: [0:16) floats flag | U1 512x64 f32 | Aj 512x64 f32 | WxT 256x256 bf16
    // total = (16 + 65536)*4 + 131072 = ~393 KB
    float* wsf  = (float*)d_ws;
    int*   flag = (int*)d_ws;
    float* U1  = wsf + 16;
    float* Aj  = U1 + 32768;
    short* WxT = (short*)(Aj + 32768);

    k_detect<<<1, 64, 0, stream>>>(A.means, flag);
    k_nodepre<bf16,  0><<<NNODE, 64, 0, stream>>>(A, flag, U1, Aj, WxT);
    k_nodepre<float, 1><<<NNODE, 64, 0, stream>>>(A, flag, U1, Aj, WxT);
    k_sake<bf16,  0><<<NNODE, 256, 0, stream>>>(A, flag, U1, Aj, WxT, d_out);
    k_sake<float, 1><<<NNODE, 256, 0, stream>>>(A, flag, U1, Aj, WxT, d_out);
}

// Round 15
// 280.246 us; speedup vs baseline: 4.7418x; 1.1230x over previous
//
#include <hip/hip_runtime.h>
#include <hip/hip_bf16.h>

typedef __hip_bfloat16 bf16;
typedef __attribute__((ext_vector_type(8))) short bf16x8;
typedef __attribute__((ext_vector_type(4))) float f32x4;

#define NNODE 512   // B*N

__device__ __forceinline__ float b2f(bf16 v){ return __bfloat162float(v); }
__device__ __forceinline__ float siluf(float x){ return x / (1.f + __expf(-x)); }
__device__ __forceinline__ float tanhfast(float x){ return 1.f - 2.f/(__expf(2.f*x)+1.f); }
__device__ __forceinline__ float celu2(float x){ return x > 0.f ? x : 2.f*(__expf(0.5f*x)-1.f); }
__device__ __forceinline__ float bs2f(short v){ union{unsigned int i; float f;} t; t.i = ((unsigned int)(unsigned short)v) << 16; return t.f; }
__device__ __forceinline__ short f2bs(float x){ union{ bf16 b; short s; } u; u.b = __float2bfloat16(x); return u.s; }

// ---- dtype-polymorphic scalar load/store -------------------------------------------
template<typename T> __device__ __forceinline__ float ldv(const void* p, int i);
template<> __device__ __forceinline__ float ldv<float>(const void* p, int i){ return ((const float*)p)[i]; }
template<> __device__ __forceinline__ float ldv<bf16 >(const void* p, int i){ return b2f(((const bf16*)p)[i]); }

template<typename T> __device__ __forceinline__ void stv(void* p, int i, float v);
template<> __device__ __forceinline__ void stv<float>(void* p, int i, float v){ ((float*)p)[i] = v; }
template<> __device__ __forceinline__ void stv<bf16 >(void* p, int i, float v){ ((bf16*)p)[i] = __float2bfloat16(v); }

// load one element as bf16 bit-pattern (short)
template<typename T> __device__ __forceinline__ short ldbs(const void* p, int i);
template<> __device__ __forceinline__ short ldbs<bf16 >(const void* p, int i){ union{ bf16 b; short s; } u; u.b = ((const bf16*)p)[i]; return u.s; }
template<> __device__ __forceinline__ short ldbs<float>(const void* p, int i){ return f2bs(((const float*)p)[i]); }

struct Args {
    const void *h,*x,*v,*Win,*bin,*means,*betas,*Wo1,*bo1,*Wo2,*bo2,*Wsem,*bsem,*Wx,
               *Wp1,*bp1,*Wp2,*bp2,*Wn1,*bn1,*Wn2,*bn2,*Wv1,*bv1,*Wv2,*Wvm;
};

// ---- dtype detector: rbf_means[0] ~ 0.0067; read as bf16 low-half of an f32 it is huge
__global__ void k_detect(const void* means, int* flag){
    if (threadIdx.x == 0){
        float v = b2f(((const bf16*)means)[0]);
        flag[0] = (fabsf(v) > 1.0f || v != v) ? 1 : 0;   // 1 => inputs are float32
    }
}

// ---- per-node precompute: U1[j] = h_j @ Wo1[0:64], Aj[j] = h_j @ Win[0:64] ---------
// Also transposes Wx -> WxT[n][k] (bf16); reads coalesced (consecutive n per thread).
template<typename T, int WANT>
__global__ void __launch_bounds__(64) k_nodepre(Args A, const int* __restrict__ flag,
                                                float* __restrict__ U1, float* __restrict__ Aj,
                                                short* __restrict__ WxT)
{
    if (flag[0] != WANT) return;
    int bn = blockIdx.x, t = threadIdx.x;
    __shared__ float sh[64];
    sh[t] = ldv<T>(A.h, bn*64 + t);
    __syncthreads();
    float u1 = 0.f;
    for (int f = 0; f < 64; ++f) u1 += sh[f] * ldv<T>(A.Wo1, f*64 + t);
    U1[bn*64 + t] = u1;
    if (t < 50){
        float a1 = 0.f;
        for (int f = 0; f < 64; ++f) a1 += sh[f] * ldv<T>(A.Win, f*50 + t);
        Aj[bn*64 + t] = a1;
    }
    // transpose Wx: 2 elements per thread, coalesced reads (consecutive n, same k)
    int e = (bn*64 + t)*2;        // 0..65534
    int k = e >> 8, n = e & 255;
    WxT[n*256 + k]     = ldbs<T>(A.Wx, k*256 + n);
    WxT[(n+1)*256 + k] = ldbs<T>(A.Wx, k*256 + n + 1);
}

// ---- fused SAKE layer: one block per (b,i) node; 256 threads (4 waves) -------------
// R14 base (315us) + (1) s_x4 precomputed once (thread=j) removing 64x-redundant
// per-lane dist work, (2) Wsem staged to LDS (broadcast reads), (3) mixing restored
// to full-width Cc[4][4] (A-frag build once, not twice) using WxT vector B-loads.
template<typename T, int WANT>
__global__ void __launch_bounds__(256) k_sake(Args A, const int* __restrict__ flag,
                                              const float* __restrict__ U1w,
                                              const float* __restrict__ Ajw,
                                              const short* __restrict__ wxt,
                                              void* __restrict__ out)
{
    if (flag[0] != WANT) return;

    int bi = blockIdx.x;
    int b = bi >> 8, i = bi & 255;
    int tid = threadIdx.x, w = tid >> 6, lane = tid & 63;

    __shared__ float s_hi[64];           // h_i                          256 B
    __shared__ bf16  s_e[256][66];       // edge features (row padded)  33.8 KB
    __shared__ float s_att[256][4];      // logits -> softmax weights      4 KB
    __shared__ float s_x4[256][4];       // xhat[3], d                     4 KB
    __shared__ float s_rbfh[4][4][52];   // per-wave scratch             3.3 KB
    __shared__ float s_mid[4][4][64];    // per-wave scratch               4 KB
    __shared__ float s_sm[1024];         // softmax scratch                4 KB
    __shared__ float s_red[768];         // comb_sum result                3 KB
    __shared__ float s_he[256];          // h_e                            1 KB
    __shared__ float s_cn[256];          // comb_norm                      1 KB
    __shared__ float s_f1[64], s_f2[64], s_f3[64], s_f4[64];  //           1 KB
    __shared__ short s_wo2[4096];        // Wo2 staged bf16                8 KB
    __shared__ short s_wo1r[3200];       // Wo1 rows 128..177 staged    6.25 KB
    __shared__ short s_wsem[256];        // Wsem staged bf16             512 B

    s_red[tid] = 0.f; s_red[tid+256] = 0.f; s_red[tid+512] = 0.f;
    if (tid < 64) s_hi[tid] = ldv<T>(A.h, bi*64 + tid);
    s_wsem[tid] = ldbs<T>(A.Wsem, tid);
    // stage Wo2 (4096) and Wo1 rbf rows (3200) into LDS
    #pragma unroll
    for (int q = 0; q < 16; ++q){
        int idx = q*256 + tid;
        s_wo2[idx] = ldbs<T>(A.Wo2, idx);
    }
    #pragma unroll
    for (int q = 0; q < 13; ++q){
        int idx = q*256 + tid;
        if (idx < 3200) s_wo1r[idx] = ldbs<T>(A.Wo1, (128 + (idx>>6))*64 + (idx&63));
    }
    __syncthreads();

    float xi0 = ldv<T>(A.x, bi*3+0), xi1 = ldv<T>(A.x, bi*3+1), xi2 = ldv<T>(A.x, bi*3+2);

    // ---- s_x4 precompute: thread j computes xhat + d once (was 64x redundant) ----
    {
        int j = tid;
        float dx = ldv<T>(A.x,(b*256+j)*3+0) - xi0;
        float dy = ldv<T>(A.x,(b*256+j)*3+1) - xi1;
        float dz = ldv<T>(A.x,(b*256+j)*3+2) - xi2;
        float dd = sqrtf(dx*dx + dy*dy + dz*dz + 1e-5f);
        float inv = 1.f/(dd + 1e-5f);
        s_x4[j][0] = dx*inv; s_x4[j][1] = dy*inv; s_x4[j][2] = dz*inv; s_x4[j][3] = dd;
    }

    // per-lane i-side constants
    float bo1v  = ldv<T>(A.bo1, lane);
    float wlast = ldv<T>(A.Wo1, 178*64 + lane);
    float bo2v  = ldv<T>(A.bo2, lane);
    float u2v = 0.f;
    for (int f = 0; f < 64; ++f) u2v += s_hi[f] * ldv<T>(A.Wo1, (64+f)*64 + lane);
    float muv = 0.f, bev = 0.f, binv = 0.f, aiv = 0.f;
    if (lane < 50){
        muv = ldv<T>(A.means, lane); bev = ldv<T>(A.betas, lane); binv = ldv<T>(A.bin, lane);
        for (int f = 0; f < 64; ++f) aiv += s_hi[f] * ldv<T>(A.Win, (64+f)*50 + lane);
    }
    __syncthreads();   // s_x4 visible to all waves

    // ================= edge phase: 16 passes x (4 waves x 4 pairs) =================
    // no in-pass barriers: s_rbfh/s_mid per-wave; dist read from s_x4 (broadcast)
    for (int pass = 0; pass < 16; ++pass){
        int j0 = pass*16 + w*4;
        float dist[4];
        #pragma unroll
        for (int pp = 0; pp < 4; ++pp) dist[pp] = s_x4[j0+pp][3];

        if (lane < 50){
            #pragma unroll
            for (int pp = 0; pp < 4; ++pp){
                int j = j0 + pp;
                float h1 = Ajw[(b*256+j)*64 + lane] + aiv + binv;
                float dd = dist[pp];
                float cut = (dd < 5.f) ? 0.5f*(__cosf(dd*0.6283185307f) + 1.f) : 0.f;
                float ex = __expf(-dd) - muv;
                s_rbfh[w][pp][lane] = cut * __expf(-bev*ex*ex) * h1;
            }
        }

        // o1 = U1[j] (precomputed) + U2[i] + b_o1 + d*w_last + rbf*h1 part (LDS weights)
        float acc[4];
        #pragma unroll
        for (int pp = 0; pp < 4; ++pp)
            acc[pp] = U1w[(b*256 + j0 + pp)*64 + lane] + u2v + bo1v + dist[pp]*wlast;
        for (int k = 0; k < 50; ++k){
            float wv = bs2f(s_wo1r[k*64 + lane]);
            #pragma unroll
            for (int pp = 0; pp < 4; ++pp) acc[pp] += s_rbfh[w][pp][k] * wv;
        }
        #pragma unroll
        for (int pp = 0; pp < 4; ++pp) s_mid[w][pp][lane] = siluf(acc[pp]);

        // o2 (LDS weights)
        float acc2[4] = {bo2v, bo2v, bo2v, bo2v};
        for (int k = 0; k < 64; ++k){
            float wv = bs2f(s_wo2[k*64 + lane]);
            #pragma unroll
            for (int pp = 0; pp < 4; ++pp) acc2[pp] += s_mid[w][pp][k] * wv;
        }
        #pragma unroll
        for (int pp = 0; pp < 4; ++pp) s_e[j0+pp][lane] = __float2bfloat16(acc2[pp]);
    }
    __syncthreads();   // single barrier: s_e now visible to all waves

    // ================= semantic attention logits (thread = j) =================
    {
        int j = tid;
        float a0 = ldv<T>(A.bsem,0), a1 = ldv<T>(A.bsem,1), a2 = ldv<T>(A.bsem,2), a3 = ldv<T>(A.bsem,3);
        for (int f = 0; f < 64; ++f){
            float ev = b2f(s_e[j][f]);
            a0 += ev * bs2f(s_wsem[f*4+0]);
            a1 += ev * bs2f(s_wsem[f*4+1]);
            a2 += ev * bs2f(s_wsem[f*4+2]);
            a3 += ev * bs2f(s_wsem[f*4+3]);
        }
        a0 = celu2(a0); a1 = celu2(a1); a2 = celu2(a2); a3 = celu2(a3);
        if (j == i){ a0 -= 1e5f; a1 -= 1e5f; a2 -= 1e5f; a3 -= 1e5f; }
        s_att[j][0] = a0; s_att[j][1] = a1; s_att[j][2] = a2; s_att[j][3] = a3;
    }
    __syncthreads();

    // ================= softmax over j (4 heads) =================
    {
        float l0 = s_att[tid][0], l1 = s_att[tid][1], l2 = s_att[tid][2], l3 = s_att[tid][3];
        s_sm[tid*4+0]=l0; s_sm[tid*4+1]=l1; s_sm[tid*4+2]=l2; s_sm[tid*4+3]=l3;
        __syncthreads();
        for (int off = 128; off > 0; off >>= 1){
            if (tid < off){
                s_sm[tid*4+0] = fmaxf(s_sm[tid*4+0], s_sm[(tid+off)*4+0]);
                s_sm[tid*4+1] = fmaxf(s_sm[tid*4+1], s_sm[(tid+off)*4+1]);
                s_sm[tid*4+2] = fmaxf(s_sm[tid*4+2], s_sm[(tid+off)*4+2]);
                s_sm[tid*4+3] = fmaxf(s_sm[tid*4+3], s_sm[(tid+off)*4+3]);
            }
            __syncthreads();
        }
        float m0 = s_sm[0], m1 = s_sm[1], m2 = s_sm[2], m3 = s_sm[3];
        __syncthreads();
        float e0 = __expf(l0-m0), e1 = __expf(l1-m1), e2 = __expf(l2-m2), e3 = __expf(l3-m3);
        s_sm[tid*4+0]=e0; s_sm[tid*4+1]=e1; s_sm[tid*4+2]=e2; s_sm[tid*4+3]=e3;
        __syncthreads();
        for (int off = 128; off > 0; off >>= 1){
            if (tid < off){
                s_sm[tid*4+0] += s_sm[(tid+off)*4+0];
                s_sm[tid*4+1] += s_sm[(tid+off)*4+1];
                s_sm[tid*4+2] += s_sm[(tid+off)*4+2];
                s_sm[tid*4+3] += s_sm[(tid+off)*4+3];
            }
            __syncthreads();
        }
        s_att[tid][0] = e0 / s_sm[0];
        s_att[tid][1] = e1 / s_sm[1];
        s_att[tid][2] = e2 / s_sm[2];
        s_att[tid][3] = e3 / s_sm[3];
    }
    __syncthreads();

    // ================= h_e[c] = sum_j e[j][f]*att[j][h], c = 4f+h =================
    {
        int f_he = tid >> 2, h_he = tid & 3;
        float he_acc = 0.f;
        for (int j2 = 0; j2 < 256; ++j2)
            he_acc += b2f(s_e[j2][f_he]) * s_att[j2][h_he];
        s_he[tid] = he_acc;
    }

    // ================= x-mixing via MFMA: P = A @ Wx, A[j,4f+h]=e[j][f]*att[j][h] ====
    // wave w owns c-slice [w*64, w*64+64), full width (Cc[4][4]); A-frags built once
    {
        int lane15 = lane & 15, quad = lane >> 4;
        int n0w = w*64;
        const short* se_s = (const short*)s_e;   // s_e[j][f] -> se_s[j*66+f]
        float comb_acc[4][3];
        #pragma unroll
        for (int nf = 0; nf < 4; ++nf){ comb_acc[nf][0]=0.f; comb_acc[nf][1]=0.f; comb_acc[nf][2]=0.f; }

        for (int jt = 0; jt < 4; ++jt){
            int jbase = jt*64;
            f32x4 Cc[4][4];
            #pragma unroll
            for (int mf = 0; mf < 4; ++mf)
                #pragma unroll
                for (int nf = 0; nf < 4; ++nf)
                    Cc[mf][nf] = (f32x4){0.f, 0.f, 0.f, 0.f};

            float am[4][4];
            #pragma unroll
            for (int mf = 0; mf < 4; ++mf){
                int jr = jbase + mf*16 + lane15;
                am[mf][0] = s_att[jr][0]; am[mf][1] = s_att[jr][1];
                am[mf][2] = s_att[jr][2]; am[mf][3] = s_att[jr][3];
            }

            for (int kk = 0; kk < 8; ++kk){
                // B fragments: one aligned 16B load each from transposed WxT[n][k]
                bf16x8 Bf[4];
                #pragma unroll
                for (int nf = 0; nf < 4; ++nf){
                    int n = n0w + nf*16 + lane15;
                    Bf[nf] = *(const bf16x8*)(wxt + n*256 + kk*32 + quad*8);
                }
                int f0 = kk*8 + quad*2;
                bf16x8 Af[4];
                #pragma unroll
                for (int mf = 0; mf < 4; ++mf){
                    int jr = jbase + mf*16 + lane15;
                    float e0 = bs2f(se_s[jr*66 + f0]);
                    float e1 = bs2f(se_s[jr*66 + f0 + 1]);
                    bf16x8 av;
                    av[0]=f2bs(e0*am[mf][0]); av[1]=f2bs(e0*am[mf][1]);
                    av[2]=f2bs(e0*am[mf][2]); av[3]=f2bs(e0*am[mf][3]);
                    av[4]=f2bs(e1*am[mf][0]); av[5]=f2bs(e1*am[mf][1]);
                    av[6]=f2bs(e1*am[mf][2]); av[7]=f2bs(e1*am[mf][3]);
                    Af[mf] = av;
                }
                #pragma unroll
                for (int mf = 0; mf < 4; ++mf)
                    #pragma unroll
                    for (int nf = 0; nf < 4; ++nf)
                        Cc[mf][nf] = __builtin_amdgcn_mfma_f32_16x16x32_bf16(Af[mf], Bf[nf], Cc[mf][nf], 0, 0, 0);
            }

            // epilogue: tanh + weighted xhat accumulation
            #pragma unroll
            for (int mf = 0; mf < 4; ++mf){
                #pragma unroll
                for (int r = 0; r < 4; ++r){
                    int j = jbase + mf*16 + quad*4 + r;
                    float x0 = s_x4[j][0], x1 = s_x4[j][1], x2 = s_x4[j][2];
                    #pragma unroll
                    for (int nf = 0; nf < 4; ++nf){
                        float cf = tanhfast(Cc[mf][nf][r]);
                        comb_acc[nf][0] += cf*x0;
                        comb_acc[nf][1] += cf*x1;
                        comb_acc[nf][2] += cf*x2;
                    }
                }
            }
        }

        // reduce over quads (j-coverage) and store: each wave owns 64 c's
        #pragma unroll
        for (int nf = 0; nf < 4; ++nf){
            #pragma unroll
            for (int d = 0; d < 3; ++d){
                float vsum = comb_acc[nf][d];
                vsum += __shfl_xor(vsum, 16);
                vsum += __shfl_xor(vsum, 32);
                if (quad == 0) s_red[(n0w + nf*16 + lane15)*3 + d] = vsum;
            }
        }
    }
    __syncthreads();

    // ================= final per-node MLPs =================
    const float sc = 1.f/256.f;
    {
        float cb0 = s_red[tid*3+0]*sc, cb1 = s_red[tid*3+1]*sc, cb2 = s_red[tid*3+2]*sc;
        s_cn[tid] = cb0*cb0 + cb1*cb1 + cb2*cb2;
    }
    __syncthreads();

    if (tid < 64){
        int f = tid;
        float acc = ldv<T>(A.bp1, f);
        for (int c = 0; c < 256; ++c) acc += s_cn[c] * ldv<T>(A.Wp1, c*64 + f);
        s_f1[f] = siluf(acc);
    }
    __syncthreads();
    if (tid < 64){
        int f = tid;
        float acc = ldv<T>(A.bp2, f);
        for (int k = 0; k < 64; ++k) acc += s_f1[k] * ldv<T>(A.Wp2, k*64 + f);
        s_f2[f] = siluf(acc);
    }
    __syncthreads();
    if (tid < 64){
        int f = tid;
        float acc = ldv<T>(A.bn1, f);
        for (int r = 0; r < 64; ++r)  acc += s_hi[r] * ldv<T>(A.Wn1, r*64 + f);
        for (int r = 0; r < 256; ++r) acc += s_he[r] * ldv<T>(A.Wn1, (64+r)*64 + f);
        for (int r = 0; r < 64; ++r)  acc += s_f2[r] * ldv<T>(A.Wn1, (320+r)*64 + f);
        s_f3[f] = siluf(acc);
    }
    __syncthreads();
    if (tid < 64){
        int f = tid;
        float acc = ldv<T>(A.bn2, f);
        for (int k = 0; k < 64; ++k) acc += s_f3[k] * ldv<T>(A.Wn2, k*64 + f);
        float hn = s_hi[f] + siluf(acc);
        stv<T>(out, bi*64 + f, hn);
        s_f4[f] = hn;
    }
    __syncthreads();
    if (tid < 64){
        int f = tid;
        float acc = ldv<T>(A.bv1, f);
        for (int k = 0; k < 64; ++k) acc += s_f4[k] * ldv<T>(A.Wv1, k*64 + f);
        float term = siluf(acc) * ldv<T>(A.Wv2, f);
        #pragma unroll
        for (int off = 32; off > 0; off >>= 1) term += __shfl_down(term, off);
        float vscale = 2.f / (1.f + __expf(-__shfl(term, 0)));

        float dv0 = 0.f, dv1 = 0.f, dv2 = 0.f;
        #pragma unroll
        for (int q = 0; q < 4; ++q){
            int c = q*64 + f;
            float wv = ldv<T>(A.Wvm, c);
            dv0 += s_red[c*3+0]*sc*wv;
            dv1 += s_red[c*3+1]*sc*wv;
            dv2 += s_red[c*3+2]*sc*wv;
        }
        #pragma unroll
        for (int off = 32; off > 0; off >>= 1){
            dv0 += __shfl_down(dv0, off);
            dv1 += __shfl_down(dv1, off);
            dv2 += __shfl_down(dv2, off);
        }
        dv0 = __shfl(dv0, 0); dv1 = __shfl(dv1, 0); dv2 = __shfl(dv2, 0);
        if (f < 3){
            float dvl = (f == 0) ? dv0 : (f == 1 ? dv1 : dv2);
            float vn = dvl + vscale * ldv<T>(A.v, bi*3 + f);
            float xn = ldv<T>(A.x, bi*3 + f) + vn;
            stv<T>(out, 32768 + bi*3 + f, xn);  // x_new
            stv<T>(out, 34304 + bi*3 + f, vn);  // v_new
        }
    }
}

extern "C" void kernel_launch(void* const* d_in, const int* in_sizes, int n_in,
                              void* d_out, int out_size, void* d_ws, size_t ws_size,
                              hipStream_t stream)
{
    Args A;
    A.h     = d_in[0];  A.x     = d_in[1];  A.v     = d_in[2];
    A.Win   = d_in[3];  A.bin   = d_in[4];  A.means = d_in[5];  A.betas = d_in[6];
    A.Wo1   = d_in[7];  A.bo1   = d_in[8];  A.Wo2   = d_in[9];  A.bo2   = d_in[10];
    A.Wsem  = d_in[11]; A.bsem  = d_in[12]; A.Wx    = d_in[13];
    A.Wp1   = d_in[14]; A.bp1   = d_in[15]; A.Wp2   = d_in[16]; A.bp2   = d_in[17];
    A.Wn1   = d_in[18]; A.bn1   = d_in[19]; A.Wn2   = d_in[20]; A.bn2   = d_in[21];
    A.Wv1   = d_in[22]; A.bv1   = d_in[23]; A.Wv2   = d_in[24]; A.Wvm   = d_in[25];

    // ws layout: [0:16) floats flag | U1 512x64 f32 | Aj 512x64 f32 | WxT 256x256 bf16
    float* wsf  = (float*)d_ws;
    int*   flag = (int*)d_ws;
    float* U1  = wsf + 16;
    float* Aj  = U1 + 32768;
    short* WxT = (short*)(Aj + 32768);

    k_detect<<<1, 64, 0, stream>>>(A.means, flag);
    k_nodepre<bf16,  0><<<NNODE, 64, 0, stream>>>(A, flag, U1, Aj, WxT);
    k_nodepre<float, 1><<<NNODE, 64, 0, stream>>>(A, flag, U1, Aj, WxT);
    k_sake<bf16,  0><<<NNODE, 256, 0, stream>>>(A, flag, U1, Aj, WxT, d_out);
    k_sake<float, 1><<<NNODE, 256, 0, stream>>>(A, flag, U1, Aj, WxT, d_out);
}

// Round 16
// 259.716 us; speedup vs baseline: 5.1167x; 1.0791x over previous
//
#include <hip/hip_runtime.h>
#include <hip/hip_bf16.h>

typedef __hip_bfloat16 bf16;
typedef __attribute__((ext_vector_type(8))) short bf16x8;
typedef __attribute__((ext_vector_type(4))) float f32x4;

#define NNODE 512   // B*N

__device__ __forceinline__ float b2f(bf16 v){ return __bfloat162float(v); }
__device__ __forceinline__ float siluf(float x){ return x / (1.f + __expf(-x)); }
__device__ __forceinline__ float tanhfast(float x){ return 1.f - 2.f/(__expf(2.f*x)+1.f); }
__device__ __forceinline__ float celu2(float x){ return x > 0.f ? x : 2.f*(__expf(0.5f*x)-1.f); }
__device__ __forceinline__ float bs2f(short v){ union{unsigned int i; float f;} t; t.i = ((unsigned int)(unsigned short)v) << 16; return t.f; }
__device__ __forceinline__ short f2bs(float x){ union{ bf16 b; short s; } u; u.b = __float2bfloat16(x); return u.s; }

// ---- dtype-polymorphic scalar load/store -------------------------------------------
template<typename T> __device__ __forceinline__ float ldv(const void* p, int i);
template<> __device__ __forceinline__ float ldv<float>(const void* p, int i){ return ((const float*)p)[i]; }
template<> __device__ __forceinline__ float ldv<bf16 >(const void* p, int i){ return b2f(((const bf16*)p)[i]); }

template<typename T> __device__ __forceinline__ void stv(void* p, int i, float v);
template<> __device__ __forceinline__ void stv<float>(void* p, int i, float v){ ((float*)p)[i] = v; }
template<> __device__ __forceinline__ void stv<bf16 >(void* p, int i, float v){ ((bf16*)p)[i] = __float2bfloat16(v); }

// load one element as bf16 bit-pattern (short)
template<typename T> __device__ __forceinline__ short ldbs(const void* p, int i);
template<> __device__ __forceinline__ short ldbs<bf16 >(const void* p, int i){ union{ bf16 b; short s; } u; u.b = ((const bf16*)p)[i]; return u.s; }
template<> __device__ __forceinline__ short ldbs<float>(const void* p, int i){ return f2bs(((const float*)p)[i]); }

struct Args {
    const void *h,*x,*v,*Win,*bin,*means,*betas,*Wo1,*bo1,*Wo2,*bo2,*Wsem,*bsem,*Wx,
               *Wp1,*bp1,*Wp2,*bp2,*Wn1,*bn1,*Wn2,*bn2,*Wv1,*bv1,*Wv2,*Wvm;
};

// ---- dtype detector: rbf_means[0] ~ 0.0067; read as bf16 low-half of an f32 it is huge
__global__ void k_detect(const void* means, int* flag){
    if (threadIdx.x == 0){
        float v = b2f(((const bf16*)means)[0]);
        flag[0] = (fabsf(v) > 1.0f || v != v) ? 1 : 0;   // 1 => inputs are float32
    }
}

// ---- per-node precompute: U1[j] (bf16) = h_j @ Wo1[0:64], Aj[j] = h_j @ Win[0:64] --
// Also transposes Wx -> WxT[n][k] (bf16).
template<typename T, int WANT>
__global__ void __launch_bounds__(64) k_nodepre(Args A, const int* __restrict__ flag,
                                                short* __restrict__ U1, float* __restrict__ Aj,
                                                short* __restrict__ WxT)
{
    if (flag[0] != WANT) return;
    int bn = blockIdx.x, t = threadIdx.x;
    __shared__ float sh[64];
    sh[t] = ldv<T>(A.h, bn*64 + t);
    __syncthreads();
    float u1 = 0.f;
    for (int f = 0; f < 64; ++f) u1 += sh[f] * ldv<T>(A.Wo1, f*64 + t);
    U1[bn*64 + t] = f2bs(u1);
    if (t < 50){
        float a1 = 0.f;
        for (int f = 0; f < 64; ++f) a1 += sh[f] * ldv<T>(A.Win, f*50 + t);
        Aj[bn*64 + t] = a1;
    }
    // transpose Wx: 2 elements per thread
    int e = (bn*64 + t)*2;        // 0..65534
    int k = e >> 8, n = e & 255;
    WxT[n*256 + k]     = ldbs<T>(A.Wx, k*256 + n);
    WxT[(n+1)*256 + k] = ldbs<T>(A.Wx, k*256 + n + 1);
}

// ---- fused SAKE layer: one block per (b,i) node; 256 threads (4 waves) -------------
// R15 base (280us) + (1) o2 edge-GEMM via MFMA (B-frags hoisted to regs from s_wo2,
// A-frags from s_mid padded to 68 f32/row, bias in C-init; quad-0 stores rows 0..3),
// (2) U1 staged to LDS as bf16 (removes the per-pass global latency; 1 block/CU is
// accepted so LDS budget up to 160KB is free).
template<typename T, int WANT>
__global__ void __launch_bounds__(256) k_sake(Args A, const int* __restrict__ flag,
                                              const short* __restrict__ U1w,
                                              const float* __restrict__ Ajw,
                                              const short* __restrict__ wxt,
                                              void* __restrict__ out)
{
    if (flag[0] != WANT) return;

    int bi = blockIdx.x;
    int b = bi >> 8, i = bi & 255;
    int tid = threadIdx.x, w = tid >> 6, lane = tid & 63;

    __shared__ float s_hi[64];           // h_i                          256 B
    __shared__ bf16  s_e[256][66];       // edge features (row padded)  33.8 KB
    __shared__ float s_att[256][4];      // logits -> softmax weights      4 KB
    __shared__ float s_x4[256][4];       // xhat[3], d                     4 KB
    __shared__ float s_rbfh[4][4][52];   // per-wave scratch             3.3 KB
    __shared__ __align__(16) float s_mid[4][4][68]; // per-wave scratch  4.25 KB (68: 16B rows, bank-safe)
    __shared__ float s_sm[1024];         // softmax scratch                4 KB
    __shared__ float s_red[768];         // comb_sum result                3 KB
    __shared__ float s_he[256];          // h_e                            1 KB
    __shared__ float s_cn[256];          // comb_norm                      1 KB
    __shared__ float s_f1[64], s_f2[64], s_f3[64], s_f4[64];  //           1 KB
    __shared__ short s_wo2[4096];        // Wo2 staged bf16                8 KB
    __shared__ short s_wo1r[3200];       // Wo1 rows 128..177 staged    6.25 KB
    __shared__ short s_wsem[256];        // Wsem staged bf16             512 B
    __shared__ __align__(16) short s_u1[256][72];   // U1 staged bf16   36.9 KB (72: 16B rows)

    s_red[tid] = 0.f; s_red[tid+256] = 0.f; s_red[tid+512] = 0.f;
    if (tid < 64) s_hi[tid] = ldv<T>(A.h, bi*64 + tid);
    s_wsem[tid] = ldbs<T>(A.Wsem, tid);
    // stage Wo2 (4096) and Wo1 rbf rows (3200) into LDS
    #pragma unroll
    for (int q = 0; q < 16; ++q){
        int idx = q*256 + tid;
        s_wo2[idx] = ldbs<T>(A.Wo2, idx);
    }
    #pragma unroll
    for (int q = 0; q < 13; ++q){
        int idx = q*256 + tid;
        if (idx < 3200) s_wo1r[idx] = ldbs<T>(A.Wo1, (128 + (idx>>6))*64 + (idx&63));
    }
    // stage U1 (bf16, one row per thread; vectorized 16B copies)
    {
        const short* src = U1w + (b*256 + tid - (b*256))*0 + (b*256)*64 + tid*64; // = U1w + (b*256+tid)*64
        short* dst = &s_u1[tid][0];
        #pragma unroll
        for (int q = 0; q < 8; ++q)
            *(uint4*)(dst + q*8) = *(const uint4*)(U1w + (b*256 + tid)*64 + q*8);
        (void)src;
    }
    __syncthreads();

    float xi0 = ldv<T>(A.x, bi*3+0), xi1 = ldv<T>(A.x, bi*3+1), xi2 = ldv<T>(A.x, bi*3+2);

    // ---- s_x4 precompute: thread j computes xhat + d once ----
    {
        int j = tid;
        float dx = ldv<T>(A.x,(b*256+j)*3+0) - xi0;
        float dy = ldv<T>(A.x,(b*256+j)*3+1) - xi1;
        float dz = ldv<T>(A.x,(b*256+j)*3+2) - xi2;
        float dd = sqrtf(dx*dx + dy*dy + dz*dz + 1e-5f);
        float inv = 1.f/(dd + 1e-5f);
        s_x4[j][0] = dx*inv; s_x4[j][1] = dy*inv; s_x4[j][2] = dz*inv; s_x4[j][3] = dd;
    }

    int lane15 = lane & 15, quad = lane >> 4;

    // per-lane i-side constants
    float bo1v  = ldv<T>(A.bo1, lane);
    float wlast = ldv<T>(A.Wo1, 178*64 + lane);
    float u2v = 0.f;
    for (int f = 0; f < 64; ++f) u2v += s_hi[f] * ldv<T>(A.Wo1, (64+f)*64 + lane);
    float muv = 0.f, bev = 0.f, binv = 0.f, aiv = 0.f;
    if (lane < 50){
        muv = ldv<T>(A.means, lane); bev = ldv<T>(A.betas, lane); binv = ldv<T>(A.bin, lane);
        for (int f = 0; f < 64; ++f) aiv += s_hi[f] * ldv<T>(A.Win, (64+f)*50 + lane);
    }
    __syncthreads();   // s_x4 + staged LDS visible to all waves

    // hoisted o2 MFMA B-fragments (pass-invariant): B[k=kk2*32+quad*8+t][n=nf*16+lane15]
    bf16x8 Bo2[2][4];
    #pragma unroll
    for (int kk2 = 0; kk2 < 2; ++kk2)
        #pragma unroll
        for (int nf = 0; nf < 4; ++nf){
            bf16x8 bv;
            #pragma unroll
            for (int t = 0; t < 8; ++t)
                bv[t] = s_wo2[(kk2*32 + quad*8 + t)*64 + nf*16 + lane15];
            Bo2[kk2][nf] = bv;
        }
    float bo2c[4];
    #pragma unroll
    for (int nf = 0; nf < 4; ++nf) bo2c[nf] = ldv<T>(A.bo2, nf*16 + lane15);

    // ================= edge phase: 16 passes x (4 waves x 4 pairs) =================
    for (int pass = 0; pass < 16; ++pass){
        int j0 = pass*16 + w*4;
        float dist[4];
        #pragma unroll
        for (int pp = 0; pp < 4; ++pp) dist[pp] = s_x4[j0+pp][3];

        if (lane < 50){
            #pragma unroll
            for (int pp = 0; pp < 4; ++pp){
                int j = j0 + pp;
                float h1 = Ajw[(b*256+j)*64 + lane] + aiv + binv;
                float dd = dist[pp];
                float cut = (dd < 5.f) ? 0.5f*(__cosf(dd*0.6283185307f) + 1.f) : 0.f;
                float ex = __expf(-dd) - muv;
                s_rbfh[w][pp][lane] = cut * __expf(-bev*ex*ex) * h1;
            }
        }

        // o1 = U1[j] (LDS) + U2[i] + b_o1 + d*w_last + rbf*h1 part (LDS weights)
        float acc[4];
        #pragma unroll
        for (int pp = 0; pp < 4; ++pp)
            acc[pp] = bs2f(s_u1[j0+pp][lane]) + u2v + bo1v + dist[pp]*wlast;
        for (int k = 0; k < 50; ++k){
            float wv = bs2f(s_wo1r[k*64 + lane]);
            #pragma unroll
            for (int pp = 0; pp < 4; ++pp) acc[pp] += s_rbfh[w][pp][k] * wv;
        }
        #pragma unroll
        for (int pp = 0; pp < 4; ++pp) s_mid[w][pp][lane] = siluf(acc[pp]);

        // o2 via MFMA: [4 pairs x 64k] @ Wo2[64k x 64n]; A rows 4..15 zero
        {
            bf16x8 av2[2];
            #pragma unroll
            for (int kk2 = 0; kk2 < 2; ++kk2){
                bf16x8 av = (bf16x8){0,0,0,0,0,0,0,0};
                if (lane15 < 4){
                    const float* mp = &s_mid[w][lane15][kk2*32 + quad*8];
                    f32x4 m0 = *(const f32x4*)mp;
                    f32x4 m1 = *(const f32x4*)(mp + 4);
                    av[0]=f2bs(m0[0]); av[1]=f2bs(m0[1]); av[2]=f2bs(m0[2]); av[3]=f2bs(m0[3]);
                    av[4]=f2bs(m1[0]); av[5]=f2bs(m1[1]); av[6]=f2bs(m1[2]); av[7]=f2bs(m1[3]);
                }
                av2[kk2] = av;
            }
            #pragma unroll
            for (int nf = 0; nf < 4; ++nf){
                f32x4 Cc2 = (f32x4){bo2c[nf], bo2c[nf], bo2c[nf], bo2c[nf]};
                Cc2 = __builtin_amdgcn_mfma_f32_16x16x32_bf16(av2[0], Bo2[0][nf], Cc2, 0, 0, 0);
                Cc2 = __builtin_amdgcn_mfma_f32_16x16x32_bf16(av2[1], Bo2[1][nf], Cc2, 0, 0, 0);
                if (quad == 0){
                    s_e[j0+0][nf*16+lane15] = __float2bfloat16(Cc2[0]);
                    s_e[j0+1][nf*16+lane15] = __float2bfloat16(Cc2[1]);
                    s_e[j0+2][nf*16+lane15] = __float2bfloat16(Cc2[2]);
                    s_e[j0+3][nf*16+lane15] = __float2bfloat16(Cc2[3]);
                }
            }
        }
    }
    __syncthreads();   // single barrier: s_e now visible to all waves

    // ================= semantic attention logits (thread = j) =================
    {
        int j = tid;
        float a0 = ldv<T>(A.bsem,0), a1 = ldv<T>(A.bsem,1), a2 = ldv<T>(A.bsem,2), a3 = ldv<T>(A.bsem,3);
        for (int f = 0; f < 64; ++f){
            float ev = b2f(s_e[j][f]);
            a0 += ev * bs2f(s_wsem[f*4+0]);
            a1 += ev * bs2f(s_wsem[f*4+1]);
            a2 += ev * bs2f(s_wsem[f*4+2]);
            a3 += ev * bs2f(s_wsem[f*4+3]);
        }
        a0 = celu2(a0); a1 = celu2(a1); a2 = celu2(a2); a3 = celu2(a3);
        if (j == i){ a0 -= 1e5f; a1 -= 1e5f; a2 -= 1e5f; a3 -= 1e5f; }
        s_att[j][0] = a0; s_att[j][1] = a1; s_att[j][2] = a2; s_att[j][3] = a3;
    }
    __syncthreads();

    // ================= softmax over j (4 heads) =================
    {
        float l0 = s_att[tid][0], l1 = s_att[tid][1], l2 = s_att[tid][2], l3 = s_att[tid][3];
        s_sm[tid*4+0]=l0; s_sm[tid*4+1]=l1; s_sm[tid*4+2]=l2; s_sm[tid*4+3]=l3;
        __syncthreads();
        for (int off = 128; off > 0; off >>= 1){
            if (tid < off){
                s_sm[tid*4+0] = fmaxf(s_sm[tid*4+0], s_sm[(tid+off)*4+0]);
                s_sm[tid*4+1] = fmaxf(s_sm[tid*4+1], s_sm[(tid+off)*4+1]);
                s_sm[tid*4+2] = fmaxf(s_sm[tid*4+2], s_sm[(tid+off)*4+2]);
                s_sm[tid*4+3] = fmaxf(s_sm[tid*4+3], s_sm[(tid+off)*4+3]);
            }
            __syncthreads();
        }
        float m0 = s_sm[0], m1 = s_sm[1], m2 = s_sm[2], m3 = s_sm[3];
        __syncthreads();
        float e0 = __expf(l0-m0), e1 = __expf(l1-m1), e2 = __expf(l2-m2), e3 = __expf(l3-m3);
        s_sm[tid*4+0]=e0; s_sm[tid*4+1]=e1; s_sm[tid*4+2]=e2; s_sm[tid*4+3]=e3;
        __syncthreads();
        for (int off = 128; off > 0; off >>= 1){
            if (tid < off){
                s_sm[tid*4+0] += s_sm[(tid+off)*4+0];
                s_sm[tid*4+1] += s_sm[(tid+off)*4+1];
                s_sm[tid*4+2] += s_sm[(tid+off)*4+2];
                s_sm[tid*4+3] += s_sm[(tid+off)*4+3];
            }
            __syncthreads();
        }
        s_att[tid][0] = e0 / s_sm[0];
        s_att[tid][1] = e1 / s_sm[1];
        s_att[tid][2] = e2 / s_sm[2];
        s_att[tid][3] = e3 / s_sm[3];
    }
    __syncthreads();

    // ================= h_e[c] = sum_j e[j][f]*att[j][h], c = 4f+h =================
    {
        int f_he = tid >> 2, h_he = tid & 3;
        float he_acc = 0.f;
        for (int j2 = 0; j2 < 256; ++j2)
            he_acc += b2f(s_e[j2][f_he]) * s_att[j2][h_he];
        s_he[tid] = he_acc;
    }

    // ================= x-mixing via MFMA: P = A @ Wx, A[j,4f+h]=e[j][f]*att[j][h] ====
    {
        int n0w = w*64;
        const short* se_s = (const short*)s_e;   // s_e[j][f] -> se_s[j*66+f]
        float comb_acc[4][3];
        #pragma unroll
        for (int nf = 0; nf < 4; ++nf){ comb_acc[nf][0]=0.f; comb_acc[nf][1]=0.f; comb_acc[nf][2]=0.f; }

        for (int jt = 0; jt < 4; ++jt){
            int jbase = jt*64;
            f32x4 Cc[4][4];
            #pragma unroll
            for (int mf = 0; mf < 4; ++mf)
                #pragma unroll
                for (int nf = 0; nf < 4; ++nf)
                    Cc[mf][nf] = (f32x4){0.f, 0.f, 0.f, 0.f};

            float am[4][4];
            #pragma unroll
            for (int mf = 0; mf < 4; ++mf){
                int jr = jbase + mf*16 + lane15;
                am[mf][0] = s_att[jr][0]; am[mf][1] = s_att[jr][1];
                am[mf][2] = s_att[jr][2]; am[mf][3] = s_att[jr][3];
            }

            for (int kk = 0; kk < 8; ++kk){
                bf16x8 Bf[4];
                #pragma unroll
                for (int nf = 0; nf < 4; ++nf){
                    int n = n0w + nf*16 + lane15;
                    Bf[nf] = *(const bf16x8*)(wxt + n*256 + kk*32 + quad*8);
                }
                int f0 = kk*8 + quad*2;
                bf16x8 Af[4];
                #pragma unroll
                for (int mf = 0; mf < 4; ++mf){
                    int jr = jbase + mf*16 + lane15;
                    float e0 = bs2f(se_s[jr*66 + f0]);
                    float e1 = bs2f(se_s[jr*66 + f0 + 1]);
                    bf16x8 av;
                    av[0]=f2bs(e0*am[mf][0]); av[1]=f2bs(e0*am[mf][1]);
                    av[2]=f2bs(e0*am[mf][2]); av[3]=f2bs(e0*am[mf][3]);
                    av[4]=f2bs(e1*am[mf][0]); av[5]=f2bs(e1*am[mf][1]);
                    av[6]=f2bs(e1*am[mf][2]); av[7]=f2bs(e1*am[mf][3]);
                    Af[mf] = av;
                }
                #pragma unroll
                for (int mf = 0; mf < 4; ++mf)
                    #pragma unroll
                    for (int nf = 0; nf < 4; ++nf)
                        Cc[mf][nf] = __builtin_amdgcn_mfma_f32_16x16x32_bf16(Af[mf], Bf[nf], Cc[mf][nf], 0, 0, 0);
            }

            #pragma unroll
            for (int mf = 0; mf < 4; ++mf){
                #pragma unroll
                for (int r = 0; r < 4; ++r){
                    int j = jbase + mf*16 + quad*4 + r;
                    float x0 = s_x4[j][0], x1 = s_x4[j][1], x2 = s_x4[j][2];
                    #pragma unroll
                    for (int nf = 0; nf < 4; ++nf){
                        float cf = tanhfast(Cc[mf][nf][r]);
                        comb_acc[nf][0] += cf*x0;
                        comb_acc[nf][1] += cf*x1;
                        comb_acc[nf][2] += cf*x2;
                    }
                }
            }
        }

        #pragma unroll
        for (int nf = 0; nf < 4; ++nf){
            #pragma unroll
            for (int d = 0; d < 3; ++d){
                float vsum = comb_acc[nf][d];
                vsum += __shfl_xor(vsum, 16);
                vsum += __shfl_xor(vsum, 32);
                if (quad == 0) s_red[(n0w + nf*16 + lane15)*3 + d] = vsum;
            }
        }
    }
    __syncthreads();

    // ================= final per-node MLPs =================
    const float sc = 1.f/256.f;
    {
        float cb0 = s_red[tid*3+0]*sc, cb1 = s_red[tid*3+1]*sc, cb2 = s_red[tid*3+2]*sc;
        s_cn[tid] = cb0*cb0 + cb1*cb1 + cb2*cb2;
    }
    __syncthreads();

    if (tid < 64){
        int f = tid;
        float acc = ldv<T>(A.bp1, f);
        for (int c = 0; c < 256; ++c) acc += s_cn[c] * ldv<T>(A.Wp1, c*64 + f);
        s_f1[f] = siluf(acc);
    }
    __syncthreads();
    if (tid < 64){
        int f = tid;
        float acc = ldv<T>(A.bp2, f);
        for (int k = 0; k < 64; ++k) acc += s_f1[k] * ldv<T>(A.Wp2, k*64 + f);
        s_f2[f] = siluf(acc);
    }
    __syncthreads();
    if (tid < 64){
        int f = tid;
        float acc = ldv<T>(A.bn1, f);
        for (int r = 0; r < 64; ++r)  acc += s_hi[r] * ldv<T>(A.Wn1, r*64 + f);
        for (int r = 0; r < 256; ++r) acc += s_he[r] * ldv<T>(A.Wn1, (64+r)*64 + f);
        for (int r = 0; r < 64; ++r)  acc += s_f2[r] * ldv<T>(A.Wn1, (320+r)*64 + f);
        s_f3[f] = siluf(acc);
    }
    __syncthreads();
    if (tid < 64){
        int f = tid;
        float acc = ldv<T>(A.bn2, f);
        for (int k = 0; k < 64; ++k) acc += s_f3[k] * ldv<T>(A.Wn2, k*64 + f);
        float hn = s_hi[f] + siluf(acc);
        stv<T>(out, bi*64 + f, hn);
        s_f4[f] = hn;
    }
    __syncthreads();
    if (tid < 64){
        int f = tid;
        float acc = ldv<T>(A.bv1, f);
        for (int k = 0; k < 64; ++k) acc += s_f4[k] * ldv<T>(A.Wv1, k*64 + f);
        float term = siluf(acc) * ldv<T>(A.Wv2, f);
        #pragma unroll
        for (int off = 32; off > 0; off >>= 1) term += __shfl_down(term, off);
        float vscale = 2.f / (1.f + __expf(-__shfl(term, 0)));

        float dv0 = 0.f, dv1 = 0.f, dv2 = 0.f;
        #pragma unroll
        for (int q = 0; q < 4; ++q){
            int c = q*64 + f;
            float wv = ldv<T>(A.Wvm, c);
            dv0 += s_red[c*3+0]*sc*wv;
            dv1 += s_red[c*3+1]*sc*wv;
            dv2 += s_red[c*3+2]*sc*wv;
        }
        #pragma unroll
        for (int off = 32; off > 0; off >>= 1){
            dv0 += __shfl_down(dv0, off);
            dv1 += __shfl_down(dv1, off);
            dv2 += __shfl_down(dv2, off);
        }
        dv0 = __shfl(dv0, 0); dv1 = __shfl(dv1, 0); dv2 = __shfl(dv2, 0);
        if (f < 3){
            float dvl = (f == 0) ? dv0 : (f == 1 ? dv1 : dv2);
            float vn = dvl + vscale * ldv<T>(A.v, bi*3 + f);
            float xn = ldv<T>(A.x, bi*3 + f) + vn;
            stv<T>(out, 32768 + bi*3 + f, xn);  // x_new
            stv<T>(out, 34304 + bi*3 + f, vn);  // v_new
        }
    }
}

extern "C" void kernel_launch(void* const* d_in, const int* in_sizes, int n_in,
                              void* d_out, int out_size, void* d_ws, size_t ws_size,
                              hipStream_t stream)
{
    Args A;
    A.h     = d_in[0];  A.x     = d_in[1];  A.v     = d_in[2];
    A.Win   = d_in[3];  A.bin   = d_in[4];  A.means = d_in[5];  A.betas = d_in[6];
    A.Wo1   = d_in[7];  A.bo1   = d_in[8];  A.Wo2   = d_in[9];  A.bo2   = d_in[10];
    A.Wsem  = d_in[11]; A.bsem  = d_in[12]; A.Wx    = d_in[13];
    A.Wp1   = d_in[14]; A.bp1   = d_in[15]; A.Wp2   = d_in[16]; A.bp2   = d_in[17];
    A.Wn1   = d_in[18]; A.bn1   = d_in[19]; A.Wn2   = d_in[20]; A.bn2   = d_in[21];
    A.Wv1   = d_in[22]; A.bv1   = d_in[23]; A.Wv2   = d_in[24]; A.Wvm   = d_in[25];

    // ws layout: flag 64B | U1 bf16 512x64 (64KB) | Aj f32 512x64 (128KB) | WxT bf16 256x256 (128KB)
    int*   flag = (int*)d_ws;
    short* U1b  = (short*)((char*)d_ws + 64);
    float* Aj   = (float*)((char*)d_ws + 64 + 65536);
    short* WxT  = (short*)((char*)d_ws + 64 + 65536 + 131072);

    k_detect<<<1, 64, 0, stream>>>(A.means, flag);
    k_nodepre<bf16,  0><<<NNODE, 64, 0, stream>>>(A, flag, U1b, Aj, WxT);
    k_nodepre<float, 1><<<NNODE, 64, 0, stream>>>(A, flag, U1b, Aj, WxT);
    k_sake<bf16,  0><<<NNODE, 256, 0, stream>>>(A, flag, U1b, Aj, WxT, d_out);
    k_sake<float, 1><<<NNODE, 256, 0, stream>>>(A, flag, U1b, Aj, WxT, d_out);
}